// Round 1
// baseline (725.720 us; speedup 1.0000x reference)
//
#include <hip/hip_runtime.h>
#include <math.h>

#define EPSF 1e-5f

constexpr int Bc = 4, Tc = 512, Dc = 1024, Mc = 128, Hc = 8, DAc = 64, DMc = 128;
constexpr int BT = Bc * Tc;      // 2048
constexpr int Xc = DAc * DMc;    // 8192

__device__ __forceinline__ float softplus_f(float x) {
    // stable: max(x,0) + log1p(exp(-|x|))
    return fmaxf(x, 0.f) + log1pf(expf(-fabsf(x)));
}

// ---------------- K0: ak = softplus(addresses), norm_k = sum_m ak ----------------
__global__ __launch_bounds__(256) void k0_ak(const float* __restrict__ addresses,
                                             float* __restrict__ ak_g,
                                             float* __restrict__ norm_k) {
    __shared__ float akl[Mc * DAc];
    int tid = threadIdx.x;
    for (int i = tid; i < Mc * DAc; i += 256) {
        float v = softplus_f(addresses[i]);
        ak_g[i] = v;
        akl[i] = v;
    }
    __syncthreads();
    if (tid < DAc) {
        float s = 0.f;
        for (int mm = 0; mm < Mc; mm++) s += akl[mm * DAc + tid];
        norm_k[tid] = s;
    }
}

// ---------------- K1: kern_m[b,a2,x] = sum_m ak[m,a2] * matrix[b,m,x] ----------------
__global__ __launch_bounds__(256) void k1_kernm(const float* __restrict__ matrix,
                                                const float* __restrict__ ak_g,
                                                float* __restrict__ kern_m) {
    __shared__ float akl[Mc * DAc];
    int tid = threadIdx.x;
    for (int i = tid; i < Mc * DAc; i += 256) akl[i] = ak_g[i];
    __syncthreads();
    int b = blockIdx.x >> 5;                 // 32 x-blocks per b
    int x = ((blockIdx.x & 31) << 8) + tid;  // 0..8191
    float acc[DAc];
#pragma unroll
    for (int a = 0; a < DAc; a++) acc[a] = 0.f;
    const float* mp = matrix + (size_t)b * Mc * Xc + x;
    for (int mm = 0; mm < Mc; mm++) {
        float v = mp[(size_t)mm * Xc];
        const float4* akv = (const float4*)(akl + mm * DAc);
#pragma unroll
        for (int a4 = 0; a4 < DAc / 4; a4++) {
            float4 q = akv[a4];
            acc[a4 * 4 + 0] = fmaf(q.x, v, acc[a4 * 4 + 0]);
            acc[a4 * 4 + 1] = fmaf(q.y, v, acc[a4 * 4 + 1]);
            acc[a4 * 4 + 2] = fmaf(q.z, v, acc[a4 * 4 + 2]);
            acc[a4 * 4 + 3] = fmaf(q.w, v, acc[a4 * 4 + 3]);
        }
    }
    float* op = kern_m + (size_t)b * DAc * Xc + x;
#pragma unroll
    for (int a = 0; a < DAc; a++) op[(size_t)a * Xc] = acc[a];
}

// ---------------- K2: kern_n[b,a2,d] = sum_m ak[m,a2] * normalizer[b,m,d] ----------------
__global__ __launch_bounds__(256) void k2_kernn(const float* __restrict__ normalizer,
                                                const float* __restrict__ ak_g,
                                                float* __restrict__ kern_n) {
    __shared__ float akl[Mc * DAc];
    int tid = threadIdx.x;
    int b = blockIdx.x;
    for (int i = tid; i < Mc * DAc; i += 256) akl[i] = ak_g[i];
    __syncthreads();
    int d = tid & 63;
    int g = tid >> 6;  // 0..3, each owns 16 a2
    float acc[16];
#pragma unroll
    for (int i = 0; i < 16; i++) acc[i] = 0.f;
    const float* np = normalizer + (size_t)b * Mc * DAc + d;
    for (int mm = 0; mm < Mc; mm++) {
        float v = np[(size_t)mm * DAc];
#pragma unroll
        for (int i = 0; i < 16; i++)
            acc[i] = fmaf(akl[mm * DAc + g * 16 + i], v, acc[i]);
    }
#pragma unroll
    for (int i = 0; i < 16; i++)
        kern_n[((size_t)b * DAc + g * 16 + i) * DAc + d] = acc[i];
}

// ---------------- Tiled f32 GEMM with optional softplus epilogue ----------------
// C (Mr x N) = act(A (Mr x K) @ [B0 | B1] + bias). Cols < N0 use B0/bias0, else B1/bias1.
// BM=64, BN=128, BK=16; 256 threads; 4x8 per thread.
template <bool SOFTPLUS>
__global__ __launch_bounds__(256) void gemm_k(const float* __restrict__ A,
                                              const float* __restrict__ B0,
                                              const float* __restrict__ B1,
                                              const float* __restrict__ bias0,
                                              const float* __restrict__ bias1,
                                              float* __restrict__ C,
                                              int Mr, int N, int K, int N0) {
    const int BM = 64, BN = 128, BK = 16;
    __shared__ float At[BK][BM];
    __shared__ float Bt[BK][BN];
    int tid = threadIdx.x;
    int r0 = blockIdx.x * BM;
    int c0 = blockIdx.y * BN;
    const float* Bsrc;
    const float* bias;
    int cb;
    if (c0 < N0) { Bsrc = B0; bias = bias0; cb = c0; }
    else         { Bsrc = B1; bias = bias1; cb = c0 - N0; }

    int ttx = tid & 15;   // col group: cols ttx*8..+7
    int tty = tid >> 4;   // row group: rows tty*4..+3
    float acc[4][8];
#pragma unroll
    for (int i = 0; i < 4; i++)
#pragma unroll
        for (int j = 0; j < 8; j++) acc[i][j] = 0.f;

    int ar = tid >> 2;            // A stage: row 0..63
    int akk = (tid & 3) * 4;      // k offset 0,4,8,12
    int bk = tid >> 4;            // B stage: k 0..15
    int bc = (tid & 15) * 8;      // col 0..120

    for (int k0 = 0; k0 < K; k0 += BK) {
        float4 av = *(const float4*)(A + (size_t)(r0 + ar) * K + k0 + akk);
        const float* bp = Bsrc + (size_t)(k0 + bk) * N0 + cb + bc;
        float4 bv0 = *(const float4*)(bp);
        float4 bv1 = *(const float4*)(bp + 4);
        __syncthreads();
        At[akk + 0][ar] = av.x;
        At[akk + 1][ar] = av.y;
        At[akk + 2][ar] = av.z;
        At[akk + 3][ar] = av.w;
        *(float4*)&Bt[bk][bc] = bv0;
        *(float4*)&Bt[bk][bc + 4] = bv1;
        __syncthreads();
#pragma unroll
        for (int k = 0; k < BK; k++) {
            float4 a0 = *(const float4*)&At[k][tty * 4];
            float4 b0 = *(const float4*)&Bt[k][ttx * 8];
            float4 b1 = *(const float4*)&Bt[k][ttx * 8 + 4];
            float ar4[4] = {a0.x, a0.y, a0.z, a0.w};
            float bc8[8] = {b0.x, b0.y, b0.z, b0.w, b1.x, b1.y, b1.z, b1.w};
#pragma unroll
            for (int i = 0; i < 4; i++)
#pragma unroll
                for (int j = 0; j < 8; j++)
                    acc[i][j] = fmaf(ar4[i], bc8[j], acc[i][j]);
        }
    }
#pragma unroll
    for (int i = 0; i < 4; i++) {
        int r = r0 + tty * 4 + i;
#pragma unroll
        for (int j = 0; j < 8; j++) {
            int c = ttx * 8 + j;
            float v = acc[i][j] + bias[cb + c];
            if (SOFTPLUS) v = softplus_f(v);
            C[(size_t)r * N + c0 + c] = v;
        }
    }
}

// ---------------- K4: fused stage1+stage2 ----------------
// Per block: b, 32 rows r = t*8+h (4 t-values, all 8 heads), all 128 m cols.
// resp[b,t,h*128+m] = (S[m]/den1) / (Sn/den1 + EPS),
//   S[m] = sum_{a2,a} aq[a2] rq[a] kern_m[b,a2,a,m]
// NOTE: resp may alias aqrq (block reads its rows into LDS before writing) —
// no __restrict__ on those two.
__global__ __launch_bounds__(256) void k4_main(const float* aqrq,
                                               const float* __restrict__ kern_m,
                                               const float* __restrict__ kern_n,
                                               const float* __restrict__ norm_k,
                                               float* resp) {
    __shared__ float aql[32][DAc];
    __shared__ float rql[32][DAc];
    __shared__ float nkl[DAc];
    __shared__ float snp[8][32];
    __shared__ float den1l[32], denl[32];
    int tid = threadIdx.x;
    int b = blockIdx.x >> 7;               // 128 blocks per b
    int r0 = (blockIdx.x & 127) * 32;      // base row in (t*8+h) space
    int t0 = r0 >> 3;

    {   // stage aq/rq: 32 rows x 64
        int row = tid >> 3;
        int a0 = (tid & 7) * 8;
        int t = t0 + (row >> 3), h = row & 7;
        const float* src = aqrq + ((size_t)(b * Tc + t) * 1024) + h * DAc + a0;
        *(float4*)&aql[row][a0] = *(const float4*)(src);
        *(float4*)&aql[row][a0 + 4] = *(const float4*)(src + 4);
        *(float4*)&rql[row][a0] = *(const float4*)(src + 512);
        *(float4*)&rql[row][a0 + 4] = *(const float4*)(src + 516);
    }
    if (tid < DAc) nkl[tid] = norm_k[tid];
    __syncthreads();

    {   // Sn partial: groups of 8 a2 per thread-group
        int row = tid & 31;
        int g = tid >> 5;  // 0..7
        const float* kn = kern_n + (size_t)b * DAc * DAc;
        float s = 0.f;
        for (int a2 = g * 8; a2 < g * 8 + 8; a2++) {
            float dotv = 0.f;
#pragma unroll
            for (int a = 0; a < DAc; a++)
                dotv = fmaf(kn[a2 * DAc + a], rql[row][a], dotv);
            s = fmaf(aql[row][a2], dotv, s);
        }
        snp[g][row] = s;
    }
    __syncthreads();
    if (tid < 32) {
        int row = tid;
        float d1 = EPSF;
#pragma unroll
        for (int a = 0; a < DAc; a++) d1 = fmaf(aql[row][a], nkl[a], d1);
        float sn = 0.f;
#pragma unroll
        for (int g = 0; g < 8; g++) sn += snp[g][row];
        den1l[row] = d1;
        denl[row] = sn / d1 + EPSF;
    }
    __syncthreads();

    // main contraction: thread = (tcol 0..15 -> 8 m-cols) x (trow 0..15 -> 2 rows)
    int tcol = tid & 15, trow = tid >> 4;
    int ra = trow * 2, rb = ra + 1;
    int c0 = tcol * 8;
    float acc0[8], acc1[8];
#pragma unroll
    for (int j = 0; j < 8; j++) { acc0[j] = 0.f; acc1[j] = 0.f; }
    const float* kp = kern_m + (size_t)b * DAc * Xc + c0;
    for (int a2 = 0; a2 < DAc; a2++) {
        float aqa = aql[ra][a2];
        float aqb = aql[rb][a2];
        const float* kpp = kp + (size_t)a2 * Xc;
#pragma unroll 4
        for (int a = 0; a < DAc; a++) {
            float4 kv0 = *(const float4*)(kpp);
            float4 kv1 = *(const float4*)(kpp + 4);
            kpp += DMc;
            float w0 = aqa * rql[ra][a];
            float w1 = aqb * rql[rb][a];
            acc0[0] = fmaf(w0, kv0.x, acc0[0]);
            acc0[1] = fmaf(w0, kv0.y, acc0[1]);
            acc0[2] = fmaf(w0, kv0.z, acc0[2]);
            acc0[3] = fmaf(w0, kv0.w, acc0[3]);
            acc0[4] = fmaf(w0, kv1.x, acc0[4]);
            acc0[5] = fmaf(w0, kv1.y, acc0[5]);
            acc0[6] = fmaf(w0, kv1.z, acc0[6]);
            acc0[7] = fmaf(w0, kv1.w, acc0[7]);
            acc1[0] = fmaf(w1, kv0.x, acc1[0]);
            acc1[1] = fmaf(w1, kv0.y, acc1[1]);
            acc1[2] = fmaf(w1, kv0.z, acc1[2]);
            acc1[3] = fmaf(w1, kv0.w, acc1[3]);
            acc1[4] = fmaf(w1, kv1.x, acc1[4]);
            acc1[5] = fmaf(w1, kv1.y, acc1[5]);
            acc1[6] = fmaf(w1, kv1.z, acc1[6]);
            acc1[7] = fmaf(w1, kv1.w, acc1[7]);
        }
    }
    __syncthreads();  // all LDS reads done before (aliased) global writes land
#pragma unroll
    for (int rr = 0; rr < 2; rr++) {
        int row = ra + rr;
        float inv1 = 1.f / den1l[row];
        float invd = 1.f / denl[row];
        float* accp = rr ? acc1 : acc0;
        int t = t0 + (row >> 3), h = row & 7;
        float* dst = resp + ((size_t)(b * Tc + t) * 1024) + h * DMc + c0;
        float4 o0, o1;
        o0.x = accp[0] * inv1 * invd;
        o0.y = accp[1] * inv1 * invd;
        o0.z = accp[2] * inv1 * invd;
        o0.w = accp[3] * inv1 * invd;
        o1.x = accp[4] * inv1 * invd;
        o1.y = accp[5] * inv1 * invd;
        o1.z = accp[6] * inv1 * invd;
        o1.w = accp[7] * inv1 * invd;
        *(float4*)dst = o0;
        *(float4*)(dst + 4) = o1;
    }
}

extern "C" void kernel_launch(void* const* d_in, const int* in_sizes, int n_in,
                              void* d_out, int out_size, void* d_ws, size_t ws_size,
                              hipStream_t stream) {
    const float* query      = (const float*)d_in[0];
    const float* matrix     = (const float*)d_in[1];
    const float* normalizer = (const float*)d_in[2];
    const float* addresses  = (const float*)d_in[3];
    const float* W_access   = (const float*)d_in[4];
    const float* b_access   = (const float*)d_in[5];
    const float* W_read     = (const float*)d_in[6];
    const float* b_read     = (const float*)d_in[7];
    const float* W_merge    = (const float*)d_in[8];
    const float* b_merge    = (const float*)d_in[9];
    float* out = (float*)d_out;
    (void)in_sizes; (void)n_in; (void)out_size; (void)ws_size;

    float* ws = (float*)d_ws;
    float* ak     = ws;                       // 8192
    float* norm_k = ws + 8192;                // 64
    float* kern_n = ws + 8192 + 64;           // 16384
    float* kern_m = ws + 32768;               // 4*64*8192 = 2097152
    float* aqrq   = ws + 32768 + 2097152;     // 2048*1024 = 2097152 (resp aliases)

    hipLaunchKernelGGL(k0_ak, dim3(1), dim3(256), 0, stream, addresses, ak, norm_k);
    hipLaunchKernelGGL(k1_kernm, dim3(128), dim3(256), 0, stream, matrix, ak, kern_m);
    hipLaunchKernelGGL(k2_kernn, dim3(Bc), dim3(256), 0, stream, normalizer, ak, kern_n);
    hipLaunchKernelGGL((gemm_k<true>), dim3(BT / 64, 1024 / 128), dim3(256), 0, stream,
                       query, W_access, W_read, b_access, b_read, aqrq,
                       BT, 1024, Dc, 512);
    hipLaunchKernelGGL(k4_main, dim3(Bc * 128), dim3(256), 0, stream,
                       aqrq, kern_m, kern_n, norm_k, aqrq);
    hipLaunchKernelGGL((gemm_k<false>), dim3(BT / 64, 1024 / 128), dim3(256), 0, stream,
                       aqrq, W_merge, W_merge, b_merge, b_merge, out,
                       BT, 1024, 1024, 1024);
}

// Round 3
// 202.517 us; speedup vs baseline: 3.5835x; 3.5835x over previous
//
#include <hip/hip_runtime.h>
#include <hip/hip_bf16.h>
#include <math.h>

#define EPSF 1e-5f

typedef __attribute__((ext_vector_type(8))) short short8;
typedef __attribute__((ext_vector_type(4))) float f32x4;

constexpr int Bc = 4, Tc = 512, Dc = 1024, Mc = 128, Hc = 8, DAc = 64, DMc = 128;
constexpr int BT = Bc * Tc;      // 2048
constexpr int Xc = DAc * DMc;    // 8192
constexpr int Rb = Tc * Hc;      // 4096 rows per batch (t*8+h)

__device__ __forceinline__ float softplus_f(float x) {
    return fmaxf(x, 0.f) + log1pf(expf(-fabsf(x)));
}
__device__ __forceinline__ short f2bf(float f) {
    __hip_bfloat16 h = __float2bfloat16(f);
    return *reinterpret_cast<short*>(&h);
}
__device__ __forceinline__ unsigned pk2(float a, float b) {
    return (unsigned)(unsigned short)f2bf(a) | ((unsigned)(unsigned short)f2bf(b) << 16);
}
// async global->LDS, 16B per lane; lds base must be wave-uniform
__device__ __forceinline__ void lds_load16(void* lds, const void* g) {
    __builtin_amdgcn_global_load_lds((const __attribute__((address_space(1))) int*)g,
                                     (__attribute__((address_space(3))) int*)lds, 16, 0, 0);
}

// ---------------- K0: ak = softplus(addresses), norm_k = sum_m ak ----------------
__global__ __launch_bounds__(256) void k0_ak(const float* __restrict__ addresses,
                                             float* __restrict__ ak_g,
                                             float* __restrict__ norm_k) {
    __shared__ float akl[Mc * DAc];
    int tid = threadIdx.x;
    for (int i = tid; i < Mc * DAc; i += 256) {
        float v = softplus_f(addresses[i]);
        ak_g[i] = v;
        akl[i] = v;
    }
    __syncthreads();
    if (tid < DAc) {
        float s = 0.f;
        for (int mm = 0; mm < Mc; mm++) s += akl[mm * DAc + tid];
        norm_k[tid] = s;
    }
}

// ---------------- K1: kern_m[b,a2,x] = sum_m ak[m,a2] * matrix[b,m,x] (f32) ----------------
__global__ __launch_bounds__(256) void k1_kernm(const float* __restrict__ matrix,
                                                const float* __restrict__ ak_g,
                                                float* __restrict__ kern_m) {
    __shared__ float akl[Mc * DAc];
    int tid = threadIdx.x;
    for (int i = tid; i < Mc * DAc; i += 256) akl[i] = ak_g[i];
    __syncthreads();
    int b = blockIdx.x >> 5;
    int x = ((blockIdx.x & 31) << 8) + tid;
    float acc[DAc];
#pragma unroll
    for (int a = 0; a < DAc; a++) acc[a] = 0.f;
    const float* mp = matrix + (size_t)b * Mc * Xc + x;
    for (int mm = 0; mm < Mc; mm++) {
        float v = mp[(size_t)mm * Xc];
        const float4* akv = (const float4*)(akl + mm * DAc);
#pragma unroll
        for (int a4 = 0; a4 < DAc / 4; a4++) {
            float4 q = akv[a4];
            acc[a4 * 4 + 0] = fmaf(q.x, v, acc[a4 * 4 + 0]);
            acc[a4 * 4 + 1] = fmaf(q.y, v, acc[a4 * 4 + 1]);
            acc[a4 * 4 + 2] = fmaf(q.z, v, acc[a4 * 4 + 2]);
            acc[a4 * 4 + 3] = fmaf(q.w, v, acc[a4 * 4 + 3]);
        }
    }
    float* op = kern_m + (size_t)b * DAc * Xc + x;
#pragma unroll
    for (int a = 0; a < DAc; a++) op[(size_t)a * Xc] = acc[a];
}

// ---------------- kT: kern_T[b][m][a2][a] (bf16) = kern_m[b][a2][a*128+m] ----------------
__global__ __launch_bounds__(256) void kT_kern(const float* __restrict__ km,
                                               __hip_bfloat16* __restrict__ kT) {
    __shared__ float tile[64][129];
    int b = blockIdx.x >> 6, a2 = blockIdx.x & 63;
    int t = threadIdx.x;
    const float* src = km + ((size_t)(b * DAc + a2)) * Xc;
    {
        int a = t >> 2, q = t & 3;
#pragma unroll
        for (int j = 0; j < 8; j++) {
            float4 v = *(const float4*)(src + a * DMc + q * 32 + j * 4);
            tile[a][q * 32 + j * 4 + 0] = v.x;
            tile[a][q * 32 + j * 4 + 1] = v.y;
            tile[a][q * 32 + j * 4 + 2] = v.z;
            tile[a][q * 32 + j * 4 + 3] = v.w;
        }
    }
    __syncthreads();
    {
        int m = t >> 1, half = t & 1;
        unsigned* d = (unsigned*)(kT + (((size_t)(b * Mc + m)) * DAc + a2) * DAc + half * 32);
#pragma unroll
        for (int j = 0; j < 16; j++)
            d[j] = pk2(tile[half * 32 + j * 2][m], tile[half * 32 + j * 2 + 1][m]);
    }
}

// ---------------- K2: kern_n[b,a2,d] = sum_m ak[m,a2] * normalizer[b,m,d] ----------------
__global__ __launch_bounds__(256) void k2_kernn(const float* __restrict__ normalizer,
                                                const float* __restrict__ ak_g,
                                                float* __restrict__ kern_n) {
    __shared__ float akl[Mc * DAc];
    int tid = threadIdx.x;
    int b = blockIdx.x;
    for (int i = tid; i < Mc * DAc; i += 256) akl[i] = ak_g[i];
    __syncthreads();
    int d = tid & 63;
    int g = tid >> 6;
    float acc[16];
#pragma unroll
    for (int i = 0; i < 16; i++) acc[i] = 0.f;
    const float* np = normalizer + (size_t)b * Mc * DAc + d;
    for (int mm = 0; mm < Mc; mm++) {
        float v = np[(size_t)mm * DAc];
#pragma unroll
        for (int i = 0; i < 16; i++)
            acc[i] = fmaf(akl[mm * DAc + g * 16 + i], v, acc[i]);
    }
#pragma unroll
    for (int i = 0; i < 16; i++)
        kern_n[((size_t)b * DAc + g * 16 + i) * DAc + d] = acc[i];
}

// ---------------- transpose+cvt: dst[n][1024] bf16 = W[k][n] ----------------
// 64x64 tile; 256 threads: 16 floats in, 16 bf16 out per thread.
__global__ __launch_bounds__(256) void tW_kern(const float* __restrict__ S0,
                                               const float* __restrict__ S1,
                                               int N0, int st0, int st1,
                                               __hip_bfloat16* __restrict__ dst) {
    __shared__ float tile[64][65];
    int kt = blockIdx.x, nt = blockIdx.y;
    int n0 = nt * 64;
    const float* S; int stride, nb;
    if (n0 < N0) { S = S0; stride = st0; nb = n0; }
    else         { S = S1; stride = st1; nb = n0 - N0; }
    int t = threadIdx.x;
    {
        int kl = t >> 2, q = t & 3;
        const float* src = S + (size_t)(kt * 64 + kl) * stride + nb + q * 16;
#pragma unroll
        for (int j = 0; j < 4; j++) {
            float4 v = *(const float4*)(src + j * 4);
            tile[kl][q * 16 + j * 4 + 0] = v.x;
            tile[kl][q * 16 + j * 4 + 1] = v.y;
            tile[kl][q * 16 + j * 4 + 2] = v.z;
            tile[kl][q * 16 + j * 4 + 3] = v.w;
        }
    }
    __syncthreads();
    {
        int nl = t >> 2, q = t & 3;
        unsigned* d = (unsigned*)(dst + (size_t)(n0 + nl) * 1024 + kt * 64 + q * 16);
#pragma unroll
        for (int j = 0; j < 8; j++)
            d[j] = pk2(tile[q * 16 + j * 2][nl], tile[q * 16 + j * 2 + 1][nl]);
    }
}

// ---------------- convert query to bf16 ----------------
__global__ __launch_bounds__(256) void convq(const float* __restrict__ q,
                                             __hip_bfloat16* __restrict__ qb) {
    int i = (blockIdx.x * 256 + threadIdx.x) * 4;
    float4 v = *(const float4*)(q + i);
    unsigned* d = (unsigned*)(qb + i);
    d[0] = pk2(v.x, v.y);
    d[1] = pk2(v.z, v.w);
}

// ---------------- k3: scale[b][row] = 1/(den1*(sn/den1+EPS)) ----------------
__global__ __launch_bounds__(256) void k3_scale(const float* __restrict__ aqrq,
                                                const float* __restrict__ kern_n,
                                                const float* __restrict__ norm_k,
                                                float* __restrict__ scale) {
    __shared__ float knl[4096];
    __shared__ float nkl[64];
    int b = blockIdx.x >> 5, ch = blockIdx.x & 31;
    int t = threadIdx.x;
    {
        const float* src = kern_n + (size_t)b * 4096;
#pragma unroll
        for (int j = 0; j < 4; j++)
            *(float4*)&knl[t * 4 + j * 1024] = *(const float4*)(src + t * 4 + j * 1024);
    }
    if (t < 64) nkl[t] = norm_k[t];
    __syncthreads();
    int row = t >> 1, g = t & 1;
    int rg = ch * 128 + row;
    int t_ = rg >> 3, h = rg & 7;
    const float* aqp = aqrq + ((size_t)(b * Tc + t_)) * 1024 + h * 64;
    float rq[64];
#pragma unroll
    for (int j = 0; j < 16; j++) {
        float4 v = *(const float4*)(aqp + 512 + j * 4);
        rq[j * 4 + 0] = v.x; rq[j * 4 + 1] = v.y; rq[j * 4 + 2] = v.z; rq[j * 4 + 3] = v.w;
    }
    float aqh[32];
#pragma unroll
    for (int j = 0; j < 8; j++) {
        float4 v = *(const float4*)(aqp + g * 32 + j * 4);
        aqh[j * 4 + 0] = v.x; aqh[j * 4 + 1] = v.y; aqh[j * 4 + 2] = v.z; aqh[j * 4 + 3] = v.w;
    }
    float sn = 0.f, d1h = 0.f;
    for (int a2l = 0; a2l < 32; a2l++) {
        int a2 = g * 32 + a2l;
        const float4* kr = (const float4*)&knl[a2 * 64];
        float dot = 0.f;
#pragma unroll
        for (int d4 = 0; d4 < 16; d4++) {
            float4 kv = kr[d4];
            dot = fmaf(kv.x, rq[d4 * 4 + 0], dot);
            dot = fmaf(kv.y, rq[d4 * 4 + 1], dot);
            dot = fmaf(kv.z, rq[d4 * 4 + 2], dot);
            dot = fmaf(kv.w, rq[d4 * 4 + 3], dot);
        }
        sn = fmaf(aqh[a2l], dot, sn);
        d1h = fmaf(aqh[a2l], nkl[a2], d1h);
    }
    sn += __shfl_xor(sn, 1);
    d1h += __shfl_xor(d1h, 1);
    if (g == 0) {
        float den1 = d1h + EPSF;
        float den = sn / den1 + EPSF;
        scale[(size_t)b * Rb + rg] = 1.f / (den1 * den);
    }
}

// ---------------- bf16 MFMA GEMM: C[M][N] = A[M][K] @ BT[N][K]^T + bias ----------------
template <bool SOFTPLUS>
__global__ __launch_bounds__(256) void gemm_bf16(const __hip_bfloat16* __restrict__ A,
                                                 const __hip_bfloat16* __restrict__ BT_,
                                                 const float* __restrict__ bias0,
                                                 const float* __restrict__ bias1, int N0,
                                                 float* __restrict__ C, int N, int K) {
    __shared__ short Ab[2][128 * 64];
    __shared__ short Bb[2][128 * 64];
    int tid = threadIdx.x, lane = tid & 63, wid = tid >> 6;
    int l15 = lane & 15, lg = lane >> 4;
    int rowblk = blockIdx.x * 128, colblk = blockIdx.y * 128;
    int wr = wid & 1, wc = wid >> 1;
    int srow = lane >> 3;
    int sk = ((lane & 7) ^ srow) * 8;   // pre-swizzled source k offset

    f32x4 acc[4][4];
#pragma unroll
    for (int i = 0; i < 4; i++)
#pragma unroll
        for (int j = 0; j < 4; j++) acc[i][j] = (f32x4){0.f, 0.f, 0.f, 0.f};

    auto stage = [&](int kbase, int buf) {
#pragma unroll
        for (int j = 0; j < 4; j++) {
            int c = wid * 4 + j;
            int row = c * 8 + srow;
            lds_load16(&Ab[buf][c * 512], A + (size_t)(rowblk + row) * K + kbase + sk);
            lds_load16(&Bb[buf][c * 512], BT_ + (size_t)(colblk + row) * K + kbase + sk);
        }
    };
    stage(0, 0);
    __syncthreads();
    int cur = 0;
    int nks = K >> 6;
    for (int ks = 0; ks < nks; ks++) {
        if (ks + 1 < nks) stage((ks + 1) << 6, cur ^ 1);
#pragma unroll
        for (int kh = 0; kh < 2; kh++) {
            short8 af[4], bfr[4];
#pragma unroll
            for (int rf = 0; rf < 4; rf++) {
                int row = wr * 64 + rf * 16 + l15;
                int ksw = (kh * 32 + lg * 8) ^ ((row & 7) << 3);
                af[rf] = *(const short8*)&Ab[cur][row * 64 + ksw];
            }
#pragma unroll
            for (int cf = 0; cf < 4; cf++) {
                int col = wc * 64 + cf * 16 + l15;
                int ksw = (kh * 32 + lg * 8) ^ ((col & 7) << 3);
                bfr[cf] = *(const short8*)&Bb[cur][col * 64 + ksw];
            }
#pragma unroll
            for (int rf = 0; rf < 4; rf++)
#pragma unroll
                for (int cf = 0; cf < 4; cf++)
                    acc[rf][cf] = __builtin_amdgcn_mfma_f32_16x16x32_bf16(
                        af[rf], bfr[cf], acc[rf][cf], 0, 0, 0);
        }
        __syncthreads();
        cur ^= 1;
    }
#pragma unroll
    for (int cf = 0; cf < 4; cf++) {
        int col = colblk + wc * 64 + cf * 16 + l15;
        float bv = (col < N0) ? bias0[col] : bias1[col - N0];
#pragma unroll
        for (int rf = 0; rf < 4; rf++) {
            int rbase = rowblk + wr * 64 + rf * 16 + lg * 4;
#pragma unroll
            for (int i = 0; i < 4; i++) {
                float v = acc[rf][cf][i] + bv;
                if (SOFTPLUS) v = softplus_f(v);
                C[(size_t)(rbase + i) * N + col] = v;
            }
        }
    }
}

// ---------------- k4: main contraction, MFMA ----------------
// num[row,m] = sum_{a2} aq[row,a2] * sum_a rq[row,a]*kern_T[b][m][a2][a]
// resp[row,m] = num * scale[row]
__global__ __launch_bounds__(256) void k4_mfma(const float* __restrict__ aqrq,
                                               const __hip_bfloat16* __restrict__ kT,
                                               const float* __restrict__ scale,
                                               __hip_bfloat16* __restrict__ resp) {
    __shared__ short Bb[2][128 * 64];   // [m][a] swizzled, one a2-slice
    __shared__ float aql[64][65];       // [row][a2] padded
    __shared__ float rql[64][65];       // [row][a]  padded
    __shared__ float scl[64];
    int tid = threadIdx.x, lane = tid & 63, wid = tid >> 6;
    int l15 = lane & 15, lg = lane >> 4;
    int b = blockIdx.x >> 6;
    int rowbase = (blockIdx.x & 63) * 64;
    int wr = wid & 1, wc = wid >> 1;
    int srow = lane >> 3;
    int sa = ((lane & 7) ^ srow) * 8;

    auto stageB = [&](int a2s, int buf) {
#pragma unroll
        for (int j = 0; j < 4; j++) {
            int c = wid * 4 + j;
            int m = c * 8 + srow;
            lds_load16(&Bb[buf][c * 512],
                       kT + (((size_t)(b * Mc + m)) * DAc + a2s) * DAc + sa);
        }
    };
    stageB(0, 0);
    {   // aq/rq rows -> padded LDS (reg-staged, 16+16 floats per thread)
        int row = tid >> 2, q = tid & 3;
        int rg = rowbase + row;
        int t_ = rg >> 3, h = rg & 7;
        const float* src = aqrq + ((size_t)(b * Tc + t_)) * 1024 + h * 64 + q * 16;
#pragma unroll
        for (int j = 0; j < 4; j++) {
            float4 v = *(const float4*)(src + j * 4);
            aql[row][q * 16 + j * 4 + 0] = v.x;
            aql[row][q * 16 + j * 4 + 1] = v.y;
            aql[row][q * 16 + j * 4 + 2] = v.z;
            aql[row][q * 16 + j * 4 + 3] = v.w;
            float4 w = *(const float4*)(src + 512 + j * 4);
            rql[row][q * 16 + j * 4 + 0] = w.x;
            rql[row][q * 16 + j * 4 + 1] = w.y;
            rql[row][q * 16 + j * 4 + 2] = w.z;
            rql[row][q * 16 + j * 4 + 3] = w.w;
        }
    }
    if (tid < 64) scl[tid] = scale[(size_t)b * Rb + rowbase + tid];
    __syncthreads();

    float rqf[2][2][8];
#pragma unroll
    for (int rf = 0; rf < 2; rf++)
#pragma unroll
        for (int kh = 0; kh < 2; kh++) {
            int row = wr * 32 + rf * 16 + l15;
            int a0 = kh * 32 + lg * 8;
#pragma unroll
            for (int j = 0; j < 8; j++) rqf[rf][kh][j] = rql[row][a0 + j];
        }

    f32x4 acc[2][4];
#pragma unroll
    for (int i = 0; i < 2; i++)
#pragma unroll
        for (int j = 0; j < 4; j++) acc[i][j] = (f32x4){0.f, 0.f, 0.f, 0.f};

    int cur = 0;
    for (int a2 = 0; a2 < 64; a2++) {
        if (a2 < 63) stageB(a2 + 1, cur ^ 1);
        float aqv[2];
#pragma unroll
        for (int rf = 0; rf < 2; rf++)
            aqv[rf] = aql[wr * 32 + rf * 16 + l15][a2];
#pragma unroll
        for (int kh = 0; kh < 2; kh++) {
            short8 af[2], bfr[4];
#pragma unroll
            for (int rf = 0; rf < 2; rf++)
#pragma unroll
                for (int j = 0; j < 8; j++)
                    af[rf][j] = f2bf(aqv[rf] * rqf[rf][kh][j]);
#pragma unroll
            for (int cf = 0; cf < 4; cf++) {
                int m = wc * 64 + cf * 16 + l15;
                int asw = (kh * 32 + lg * 8) ^ ((m & 7) << 3);
                bfr[cf] = *(const short8*)&Bb[cur][m * 64 + asw];
            }
#pragma unroll
            for (int rf = 0; rf < 2; rf++)
#pragma unroll
                for (int cf = 0; cf < 4; cf++)
                    acc[rf][cf] = __builtin_amdgcn_mfma_f32_16x16x32_bf16(
                        af[rf], bfr[cf], acc[rf][cf], 0, 0, 0);
        }
        __syncthreads();
        cur ^= 1;
    }
#pragma unroll
    for (int rf = 0; rf < 2; rf++) {
#pragma unroll
        for (int i = 0; i < 4; i++) {
            int rl = wr * 32 + rf * 16 + lg * 4 + i;
            int rg = rowbase + rl;
            float s = scl[rl];
            int t_ = rg >> 3, h = rg & 7;
            __hip_bfloat16* dst = resp + ((size_t)(b * Tc + t_)) * 1024 + h * DMc;
#pragma unroll
            for (int cf = 0; cf < 4; cf++) {
                int m = wc * 64 + cf * 16 + l15;
                dst[m] = __float2bfloat16(acc[rf][cf][i] * s);
            }
        }
    }
}

extern "C" void kernel_launch(void* const* d_in, const int* in_sizes, int n_in,
                              void* d_out, int out_size, void* d_ws, size_t ws_size,
                              hipStream_t stream) {
    const float* query      = (const float*)d_in[0];
    const float* matrix     = (const float*)d_in[1];
    const float* normalizer = (const float*)d_in[2];
    const float* addresses  = (const float*)d_in[3];
    const float* W_access   = (const float*)d_in[4];
    const float* b_access   = (const float*)d_in[5];
    const float* W_read     = (const float*)d_in[6];
    const float* b_read     = (const float*)d_in[7];
    const float* W_merge    = (const float*)d_in[8];
    const float* b_merge    = (const float*)d_in[9];
    float* out = (float*)d_out;
    (void)in_sizes; (void)n_in; (void)out_size; (void)ws_size;

    // ws layout (float offsets). kern_m region (8.4 MB) is reused after kT_kern:
    //   lo half -> qb (bf16), hi half -> resp (bf16).
    float* ws     = (float*)d_ws;
    float* ak     = ws;                        // 8192
    float* norm_k = ws + 8192;                 // 64
    float* kern_n = ws + 8320;                 // 16384
    float* scale  = ws + 24704;                // 16384
    float* aqrq   = ws + 65536;                // 2,097,152 f32
    float* kern_m = ws + 2162688;              // 2,097,152 f32 (dead after kT_kern)
    __hip_bfloat16* qb   = (__hip_bfloat16*)(ws + 2162688);            // 2,097,152 bf16
    __hip_bfloat16* resp = (__hip_bfloat16*)(ws + 2162688 + 1048576);  // 2,097,152 bf16
    __hip_bfloat16* kT   = (__hip_bfloat16*)(ws + 4259840);            // 2,097,152 bf16
    __hip_bfloat16* WpT  = (__hip_bfloat16*)(ws + 5308416);            // 1,048,576 bf16
    __hip_bfloat16* WmT  = (__hip_bfloat16*)(ws + 5832704);            // 1,048,576 bf16
    // total: 6,356,992 floats = 25.4 MB

    hipLaunchKernelGGL(k0_ak, dim3(1), dim3(256), 0, stream, addresses, ak, norm_k);
    hipLaunchKernelGGL(k1_kernm, dim3(128), dim3(256), 0, stream, matrix, ak, kern_m);
    hipLaunchKernelGGL(kT_kern, dim3(256), dim3(256), 0, stream, kern_m, kT);
    hipLaunchKernelGGL(k2_kernn, dim3(Bc), dim3(256), 0, stream, normalizer, ak, kern_n);
    hipLaunchKernelGGL(convq, dim3(2048), dim3(256), 0, stream, query, qb);
    hipLaunchKernelGGL(tW_kern, dim3(16, 16), dim3(256), 0, stream,
                       W_access, W_read, 512, 512, 512, WpT);
    hipLaunchKernelGGL(tW_kern, dim3(16, 16), dim3(256), 0, stream,
                       W_merge, W_merge, 1024, 1024, 1024, WmT);
    hipLaunchKernelGGL((gemm_bf16<true>), dim3(16, 8), dim3(256), 0, stream,
                       qb, WpT, b_access, b_read, 512, aqrq, 1024, 1024);
    hipLaunchKernelGGL(k3_scale, dim3(128), dim3(256), 0, stream,
                       aqrq, kern_n, norm_k, scale);
    hipLaunchKernelGGL(k4_mfma, dim3(256), dim3(256), 0, stream,
                       aqrq, kT, scale, resp);
    hipLaunchKernelGGL((gemm_bf16<false>), dim3(16, 8), dim3(256), 0, stream,
                       resp, WmT, b_merge, b_merge, 2048, out, 1024, 1024);
}

// Round 5
// 157.847 us; speedup vs baseline: 4.5976x; 1.2830x over previous
//
#include <hip/hip_runtime.h>
#include <hip/hip_bf16.h>
#include <math.h>

#define EPSF 1e-5f

typedef __attribute__((ext_vector_type(8))) short short8;
typedef __attribute__((ext_vector_type(4))) float f32x4;
typedef _Float16 half8 __attribute__((ext_vector_type(8)));

constexpr int Bc = 4, Tc = 512, Dc = 1024, Mc = 128, Hc = 8, DAc = 64, DMc = 128;
constexpr int BT = Bc * Tc;      // 2048
constexpr int Xc = DAc * DMc;    // 8192
constexpr int Rb = Tc * Hc;      // 4096 rows per batch (t*8+h)

__device__ __forceinline__ float softplus_f(float x) {
    return fmaxf(x, 0.f) + log1pf(expf(-fabsf(x)));
}
__device__ __forceinline__ short f2bf(float f) {
    __hip_bfloat16 h = __float2bfloat16(f);
    return *reinterpret_cast<short*>(&h);
}
__device__ __forceinline__ unsigned pk2(float a, float b) {
    return (unsigned)(unsigned short)f2bf(a) | ((unsigned)(unsigned short)f2bf(b) << 16);
}
// async global->LDS, 16B per lane; lds base must be wave-uniform
__device__ __forceinline__ void lds_load16(void* lds, const void* g) {
    __builtin_amdgcn_global_load_lds((const __attribute__((address_space(1))) int*)g,
                                     (__attribute__((address_space(3))) int*)lds, 16, 0, 0);
}

// ---------------- K0: ak = softplus(addresses), norm_k, akT (f16 [a2][mm]) ----------------
__global__ __launch_bounds__(256) void k0_ak(const float* __restrict__ addresses,
                                             float* __restrict__ ak_g,
                                             float* __restrict__ norm_k,
                                             _Float16* __restrict__ akT) {
    __shared__ float akl[Mc * DAc];
    int tid = threadIdx.x;
    for (int i = tid; i < Mc * DAc; i += 256) {
        float v = softplus_f(addresses[i]);
        ak_g[i] = v;
        akl[i] = v;
    }
    __syncthreads();
    if (tid < DAc) {
        float s = 0.f;
        for (int mm = 0; mm < Mc; mm++) s += akl[mm * DAc + tid];
        norm_k[tid] = s;
    }
    {   // akT[a2][mm] f16
        int a2 = tid >> 2, q = tid & 3;
#pragma unroll
        for (int j = 0; j < 32; j++)
            akT[a2 * Mc + q * 32 + j] = (_Float16)akl[(q * 32 + j) * DAc + a2];
    }
}

// ---------------- k1t: kern2[b][a][m][a2] (f16) = sum_mm matrix[b][mm][a][m]*ak[mm][a2] ----
// One block per (b,a): 128x64 output, K=128 (4 steps of 32), MFMA 16x16x32 f16.
__global__ __launch_bounds__(256) void k1t_mfma(const float* __restrict__ matrix,
                                                const _Float16* __restrict__ akT,
                                                _Float16* __restrict__ kern2) {
    __shared__ float T[32][132];         // [mm][m] f32 staging (pad 4)
    __shared__ _Float16 At[128][40];     // [m][mm-chunk] f16 (pad to 40 els = 80B rows)
    int tid = threadIdx.x, lane = tid & 63, wid = tid >> 6;
    int l15 = lane & 15, lg = lane >> 4;
    int b = blockIdx.x >> 6, a = blockIdx.x & 63;
    int wr = wid & 1, wc = wid >> 1;

    // B-fragments (akT) for all 4 k-steps, held in registers
    half8 bfrag[2][4];
#pragma unroll
    for (int cf = 0; cf < 2; cf++)
#pragma unroll
        for (int ks = 0; ks < 4; ks++)
            bfrag[cf][ks] = *(const half8*)(akT + (wc * 32 + cf * 16 + l15) * Mc
                                            + ks * 32 + lg * 8);

    const float* msrc = matrix + (size_t)b * Mc * Xc + a * DMc;
    int r = tid >> 3, ms = (tid & 7) * 16;     // stage: row mm=r, 16 m's
    int tm = tid >> 1, tk0 = (tid & 1) * 16;   // transpose: m=tm, 16 mm's

    f32x4 acc[4][2];
#pragma unroll
    for (int i = 0; i < 4; i++)
#pragma unroll
        for (int j = 0; j < 2; j++) acc[i][j] = (f32x4){0.f, 0.f, 0.f, 0.f};

    float4 ld[4];
#pragma unroll
    for (int j = 0; j < 4; j++)
        ld[j] = *(const float4*)(msrc + (size_t)r * Xc + ms + j * 4);

    for (int s = 0; s < 4; s++) {
#pragma unroll
        for (int j = 0; j < 4; j++) *(float4*)&T[r][ms + j * 4] = ld[j];
        __syncthreads();
        if (s < 3) {
#pragma unroll
            for (int j = 0; j < 4; j++)
                ld[j] = *(const float4*)(msrc + (size_t)((s + 1) * 32 + r) * Xc + ms + j * 4);
        }
        {   // transpose T -> At (f16)
            half8 lo, hi;
#pragma unroll
            for (int j = 0; j < 8; j++) lo[j] = (_Float16)T[tk0 + j][tm];
#pragma unroll
            for (int j = 0; j < 8; j++) hi[j] = (_Float16)T[tk0 + 8 + j][tm];
            *(half8*)&At[tm][tk0] = lo;
            *(half8*)&At[tm][tk0 + 8] = hi;
        }
        __syncthreads();
#pragma unroll
        for (int rf = 0; rf < 4; rf++) {
            int row = wr * 64 + rf * 16 + l15;
            half8 af = *(const half8*)&At[row][lg * 8];
#pragma unroll
            for (int cf = 0; cf < 2; cf++)
                acc[rf][cf] = __builtin_amdgcn_mfma_f32_16x16x32_f16(
                    af, bfrag[cf][s], acc[rf][cf], 0, 0, 0);
        }
        __syncthreads();
    }
    _Float16* dst = kern2 + ((size_t)(b * 64 + a)) * Mc * DAc;
#pragma unroll
    for (int rf = 0; rf < 4; rf++)
#pragma unroll
        for (int cf = 0; cf < 2; cf++) {
            int a2 = wc * 32 + cf * 16 + l15;
#pragma unroll
            for (int i = 0; i < 4; i++) {
                int mrow = wr * 64 + rf * 16 + lg * 4 + i;
                dst[mrow * DAc + a2] = (_Float16)acc[rf][cf][i];
            }
        }
}

// ---------------- K2: kern_n[b,a2,d] = sum_m ak[m,a2] * normalizer[b,m,d] ----------------
__global__ __launch_bounds__(256) void k2_kernn(const float* __restrict__ normalizer,
                                                const float* __restrict__ ak_g,
                                                float* __restrict__ kern_n) {
    __shared__ float akl[Mc * DAc];
    int tid = threadIdx.x;
    int b = blockIdx.x;
    for (int i = tid; i < Mc * DAc; i += 256) akl[i] = ak_g[i];
    __syncthreads();
    int d = tid & 63;
    int g = tid >> 6;
    float acc[16];
#pragma unroll
    for (int i = 0; i < 16; i++) acc[i] = 0.f;
    const float* np = normalizer + (size_t)b * Mc * DAc + d;
    for (int mm = 0; mm < Mc; mm++) {
        float v = np[(size_t)mm * DAc];
#pragma unroll
        for (int i = 0; i < 16; i++)
            acc[i] = fmaf(akl[mm * DAc + g * 16 + i], v, acc[i]);
    }
#pragma unroll
    for (int i = 0; i < 16; i++)
        kern_n[((size_t)b * DAc + g * 16 + i) * DAc + d] = acc[i];
}

// ---------------- transpose+cvt: dst[n][1024] bf16 = W[k][n] ----------------
__global__ __launch_bounds__(256) void tW_kern(const float* __restrict__ S0,
                                               const float* __restrict__ S1,
                                               int N0, int st0, int st1,
                                               __hip_bfloat16* __restrict__ dst) {
    __shared__ float tile[64][65];
    int kt = blockIdx.x, nt = blockIdx.y;
    int n0 = nt * 64;
    const float* S; int stride, nb;
    if (n0 < N0) { S = S0; stride = st0; nb = n0; }
    else         { S = S1; stride = st1; nb = n0 - N0; }
    int t = threadIdx.x;
    {
        int kl = t >> 2, q = t & 3;
        const float* src = S + (size_t)(kt * 64 + kl) * stride + nb + q * 16;
#pragma unroll
        for (int j = 0; j < 4; j++) {
            float4 v = *(const float4*)(src + j * 4);
            tile[kl][q * 16 + j * 4 + 0] = v.x;
            tile[kl][q * 16 + j * 4 + 1] = v.y;
            tile[kl][q * 16 + j * 4 + 2] = v.z;
            tile[kl][q * 16 + j * 4 + 3] = v.w;
        }
    }
    __syncthreads();
    {
        int nl = t >> 2, q = t & 3;
        unsigned* d = (unsigned*)(dst + (size_t)(n0 + nl) * 1024 + kt * 64 + q * 16);
#pragma unroll
        for (int j = 0; j < 8; j++)
            d[j] = pk2(tile[q * 16 + j * 2][nl], tile[q * 16 + j * 2 + 1][nl]);
    }
}

// ---------------- convert query to bf16 ----------------
__global__ __launch_bounds__(256) void convq(const float* __restrict__ q,
                                             __hip_bfloat16* __restrict__ qb) {
    int i = (blockIdx.x * 256 + threadIdx.x) * 4;
    float4 v = *(const float4*)(q + i);
    unsigned* d = (unsigned*)(qb + i);
    d[0] = pk2(v.x, v.y);
    d[1] = pk2(v.z, v.w);
}

// ---------------- k3: scale[b][row] = 1/(den1*(sn/den1+EPS)) ----------------
__global__ __launch_bounds__(256) void k3_scale(const float* __restrict__ aqrq,
                                                const float* __restrict__ kern_n,
                                                const float* __restrict__ norm_k,
                                                float* __restrict__ scale) {
    __shared__ float knl[4096];
    __shared__ float nkl[64];
    int b = blockIdx.x >> 5, ch = blockIdx.x & 31;
    int t = threadIdx.x;
    {
        const float* src = kern_n + (size_t)b * 4096;
#pragma unroll
        for (int j = 0; j < 4; j++)
            *(float4*)&knl[t * 4 + j * 1024] = *(const float4*)(src + t * 4 + j * 1024);
    }
    if (t < 64) nkl[t] = norm_k[t];
    __syncthreads();
    int row = t >> 1, g = t & 1;
    int rg = ch * 128 + row;
    int t_ = rg >> 3, h = rg & 7;
    const float* aqp = aqrq + ((size_t)(b * Tc + t_)) * 1024 + h * 64;
    float rq[64];
#pragma unroll
    for (int j = 0; j < 16; j++) {
        float4 v = *(const float4*)(aqp + 512 + j * 4);
        rq[j * 4 + 0] = v.x; rq[j * 4 + 1] = v.y; rq[j * 4 + 2] = v.z; rq[j * 4 + 3] = v.w;
    }
    float aqh[32];
#pragma unroll
    for (int j = 0; j < 8; j++) {
        float4 v = *(const float4*)(aqp + g * 32 + j * 4);
        aqh[j * 4 + 0] = v.x; aqh[j * 4 + 1] = v.y; aqh[j * 4 + 2] = v.z; aqh[j * 4 + 3] = v.w;
    }
    float sn = 0.f, d1h = 0.f;
    for (int a2l = 0; a2l < 32; a2l++) {
        int a2 = g * 32 + a2l;
        const float4* kr = (const float4*)&knl[a2 * 64];
        float dot = 0.f;
#pragma unroll
        for (int d4 = 0; d4 < 16; d4++) {
            float4 kv = kr[d4];
            dot = fmaf(kv.x, rq[d4 * 4 + 0], dot);
            dot = fmaf(kv.y, rq[d4 * 4 + 1], dot);
            dot = fmaf(kv.z, rq[d4 * 4 + 2], dot);
            dot = fmaf(kv.w, rq[d4 * 4 + 3], dot);
        }
        sn = fmaf(aqh[a2l], dot, sn);
        d1h = fmaf(aqh[a2l], nkl[a2], d1h);
    }
    sn += __shfl_xor(sn, 1);
    d1h += __shfl_xor(d1h, 1);
    if (g == 0) {
        float den1 = d1h + EPSF;
        float den = sn / den1 + EPSF;
        scale[(size_t)b * Rb + rg] = 1.f / (den1 * den);
    }
}

// ---------------- bf16 MFMA GEMM: C[M][N] = A[M][K] @ BT[N][K]^T + bias ----------------
template <bool SOFTPLUS>
__global__ __launch_bounds__(256) void gemm_bf16(const __hip_bfloat16* __restrict__ A,
                                                 const __hip_bfloat16* __restrict__ BT_,
                                                 const float* __restrict__ bias0,
                                                 const float* __restrict__ bias1, int N0,
                                                 float* __restrict__ C, int N, int K) {
    __shared__ short Ab[2][128 * 64];
    __shared__ short Bb[2][128 * 64];
    int tid = threadIdx.x, lane = tid & 63, wid = tid >> 6;
    int l15 = lane & 15, lg = lane >> 4;
    int rowblk = blockIdx.x * 128, colblk = blockIdx.y * 128;
    int wr = wid & 1, wc = wid >> 1;
    int srow = lane >> 3;
    int sk = ((lane & 7) ^ srow) * 8;

    f32x4 acc[4][4];
#pragma unroll
    for (int i = 0; i < 4; i++)
#pragma unroll
        for (int j = 0; j < 4; j++) acc[i][j] = (f32x4){0.f, 0.f, 0.f, 0.f};

    auto stage = [&](int kbase, int buf) {
#pragma unroll
        for (int j = 0; j < 4; j++) {
            int c = wid * 4 + j;
            int row = c * 8 + srow;
            lds_load16(&Ab[buf][c * 512], A + (size_t)(rowblk + row) * K + kbase + sk);
            lds_load16(&Bb[buf][c * 512], BT_ + (size_t)(colblk + row) * K + kbase + sk);
        }
    };
    stage(0, 0);
    __syncthreads();
    int cur = 0;
    int nks = K >> 6;
    for (int ks = 0; ks < nks; ks++) {
        if (ks + 1 < nks) stage((ks + 1) << 6, cur ^ 1);
#pragma unroll
        for (int kh = 0; kh < 2; kh++) {
            short8 af[4], bfr[4];
#pragma unroll
            for (int rf = 0; rf < 4; rf++) {
                int row = wr * 64 + rf * 16 + l15;
                int ksw = (kh * 32 + lg * 8) ^ ((row & 7) << 3);
                af[rf] = *(const short8*)&Ab[cur][row * 64 + ksw];
            }
#pragma unroll
            for (int cf = 0; cf < 4; cf++) {
                int col = wc * 64 + cf * 16 + l15;
                int ksw = (kh * 32 + lg * 8) ^ ((col & 7) << 3);
                bfr[cf] = *(const short8*)&Bb[cur][col * 64 + ksw];
            }
#pragma unroll
            for (int rf = 0; rf < 4; rf++)
#pragma unroll
                for (int cf = 0; cf < 4; cf++)
                    acc[rf][cf] = __builtin_amdgcn_mfma_f32_16x16x32_bf16(
                        af[rf], bfr[cf], acc[rf][cf], 0, 0, 0);
        }
        __syncthreads();
        cur ^= 1;
    }
#pragma unroll
    for (int cf = 0; cf < 4; cf++) {
        int col = colblk + wc * 64 + cf * 16 + l15;
        float bv = (col < N0) ? bias0[col] : bias1[col - N0];
#pragma unroll
        for (int rf = 0; rf < 4; rf++) {
            int rbase = rowblk + wr * 64 + rf * 16 + lg * 4;
#pragma unroll
            for (int i = 0; i < 4; i++) {
                float v = acc[rf][cf][i] + bv;
                if (SOFTPLUS) v = softplus_f(v);
                C[(size_t)(rbase + i) * N + col] = v;
            }
        }
    }
}

// ---------------- k4: main contraction over a-slices, f16 MFMA ----------------
// num[row,m] = sum_a rq[row,a] * sum_a2 aq[row,a2] * kern2[b][a][m][a2]
// Block: 64 rows x 64 m-cols (mh half). Grid 4b x 64rc x 2mh = 512.
__global__ __launch_bounds__(256) void k4_mfma(const float* __restrict__ aqrq,
                                               const _Float16* __restrict__ kern2,
                                               const float* __restrict__ scale,
                                               __hip_bfloat16* __restrict__ resp) {
    __shared__ _Float16 Bb[2][64 * 64];  // one a-slice [mloc][a2], XOR-swizzled chunks
    __shared__ float aql[64][68];
    __shared__ float rql[64][68];
    __shared__ float scl[64];
    int tid = threadIdx.x, lane = tid & 63, wid = tid >> 6;
    int l15 = lane & 15, lg = lane >> 4;
    int b = blockIdx.x >> 7;
    int rc = (blockIdx.x >> 1) & 63;
    int mh = blockIdx.x & 1;
    int rowbase = rc * 64;
    int wr = wid & 1, wc = wid >> 1;

    auto stageB = [&](int a_, int buf) {
#pragma unroll
        for (int j = 0; j < 2; j++) {
            int c = wid * 2 + j;                       // 8 m-rows per 1KB load
            int m = c * 8 + (lane >> 3);
            int sa = ((lane & 7) ^ (lane >> 3)) * 8;   // pre-swizzled a2-chunk
            lds_load16(&Bb[buf][c * 512],
                       kern2 + (((size_t)(b * 64 + a_)) * Mc + mh * 64 + m) * DAc + sa);
        }
    };
    stageB(0, 0);
    {   // aq/rq rows -> LDS (16+16 floats per thread)
        int row = tid >> 2, q = tid & 3;
        int rg = rowbase + row;
        int t_ = rg >> 3, h = rg & 7;
        const float* src = aqrq + ((size_t)(b * Tc + t_)) * 1024 + h * 64 + q * 16;
#pragma unroll
        for (int j = 0; j < 4; j++) {
            float4 v = *(const float4*)(src + j * 4);
            aql[row][q * 16 + j * 4 + 0] = v.x;
            aql[row][q * 16 + j * 4 + 1] = v.y;
            aql[row][q * 16 + j * 4 + 2] = v.z;
            aql[row][q * 16 + j * 4 + 3] = v.w;
            float4 w = *(const float4*)(src + 512 + j * 4);
            rql[row][q * 16 + j * 4 + 0] = w.x;
            rql[row][q * 16 + j * 4 + 1] = w.y;
            rql[row][q * 16 + j * 4 + 2] = w.z;
            rql[row][q * 16 + j * 4 + 3] = w.w;
        }
    }
    if (tid < 64) scl[tid] = scale[(size_t)b * Rb + rowbase + tid];
    __syncthreads();

    // packed f16 aq fragments (loop-invariant): aqp[rf][kh]
    half8 aqp[2][2];
#pragma unroll
    for (int rf = 0; rf < 2; rf++)
#pragma unroll
        for (int kh = 0; kh < 2; kh++) {
            int row = wr * 32 + rf * 16 + l15;
#pragma unroll
            for (int j = 0; j < 8; j++)
                aqp[rf][kh][j] = (_Float16)aql[row][kh * 32 + lg * 8 + j];
        }

    f32x4 acc[2][2];
#pragma unroll
    for (int i = 0; i < 2; i++)
#pragma unroll
        for (int j = 0; j < 2; j++) acc[i][j] = (f32x4){0.f, 0.f, 0.f, 0.f};

    int cur = 0;
    for (int a = 0; a < 64; a++) {
        if (a < 63) stageB(a + 1, cur ^ 1);
        _Float16 h0 = (_Float16)rql[wr * 32 + l15][a];
        _Float16 h1 = (_Float16)rql[wr * 32 + 16 + l15][a];
        half8 rb0 = {h0, h0, h0, h0, h0, h0, h0, h0};
        half8 rb1 = {h1, h1, h1, h1, h1, h1, h1, h1};
#pragma unroll
        for (int kh = 0; kh < 2; kh++) {
#pragma unroll
            for (int cf = 0; cf < 2; cf++) {
                int mloc = wc * 32 + cf * 16 + l15;
                int ch = (kh * 4 + lg) ^ (mloc & 7);
                half8 bf = *(const half8*)&Bb[cur][mloc * 64 + ch * 8];
                acc[0][cf] = __builtin_amdgcn_mfma_f32_16x16x32_f16(
                    aqp[0][kh] * rb0, bf, acc[0][cf], 0, 0, 0);
                acc[1][cf] = __builtin_amdgcn_mfma_f32_16x16x32_f16(
                    aqp[1][kh] * rb1, bf, acc[1][cf], 0, 0, 0);
            }
        }
        __syncthreads();
        cur ^= 1;
    }
#pragma unroll
    for (int rf = 0; rf < 2; rf++) {
#pragma unroll
        for (int i = 0; i < 4; i++) {
            int rl = wr * 32 + rf * 16 + lg * 4 + i;
            int rg = rowbase + rl;
            float s = scl[rl];
            int t_ = rg >> 3, h = rg & 7;
            __hip_bfloat16* dst = resp + ((size_t)(b * Tc + t_)) * 1024 + h * DMc + mh * 64;
#pragma unroll
            for (int cf = 0; cf < 2; cf++) {
                int m = wc * 32 + cf * 16 + l15;
                dst[m] = __float2bfloat16(acc[rf][cf][i] * s);
            }
        }
    }
}

extern "C" void kernel_launch(void* const* d_in, const int* in_sizes, int n_in,
                              void* d_out, int out_size, void* d_ws, size_t ws_size,
                              hipStream_t stream) {
    const float* query      = (const float*)d_in[0];
    const float* matrix     = (const float*)d_in[1];
    const float* normalizer = (const float*)d_in[2];
    const float* addresses  = (const float*)d_in[3];
    const float* W_access   = (const float*)d_in[4];
    const float* b_access   = (const float*)d_in[5];
    const float* W_read     = (const float*)d_in[6];
    const float* b_read     = (const float*)d_in[7];
    const float* W_merge    = (const float*)d_in[8];
    const float* b_merge    = (const float*)d_in[9];
    float* out = (float*)d_out;
    (void)in_sizes; (void)n_in; (void)out_size; (void)ws_size;

    float* ws     = (float*)d_ws;
    float* ak     = ws;                        // 8192
    float* norm_k = ws + 8192;                 // 64 (+pad)
    float* kern_n = ws + 8320;                 // 16384
    float* scale  = ws + 24704;                // 16384
    _Float16* akT = (_Float16*)(ws + 41088);   // 8192 f16 = 4096 f
    float* aqrq   = ws + 65536;                // 2,097,152 f32
    _Float16* kern2 = (_Float16*)(ws + 2162688);              // 2,097,152 f16 = 1,048,576 f
    __hip_bfloat16* qb   = (__hip_bfloat16*)(ws + 3211264);   // 1,048,576 f
    __hip_bfloat16* resp = (__hip_bfloat16*)(ws + 4259840);   // 1,048,576 f
    __hip_bfloat16* WpT  = (__hip_bfloat16*)(ws + 5308416);   // 524,288 f
    __hip_bfloat16* WmT  = (__hip_bfloat16*)(ws + 5832704);   // 524,288 f
    // total 6,356,992 floats = 25.4 MB

    hipLaunchKernelGGL(k0_ak, dim3(1), dim3(256), 0, stream, addresses, ak, norm_k, akT);
    hipLaunchKernelGGL(k1t_mfma, dim3(256), dim3(256), 0, stream, matrix, akT, kern2);
    hipLaunchKernelGGL(k2_kernn, dim3(Bc), dim3(256), 0, stream, normalizer, ak, kern_n);
    hipLaunchKernelGGL(convq, dim3(2048), dim3(256), 0, stream, query, qb);
    hipLaunchKernelGGL(tW_kern, dim3(16, 16), dim3(256), 0, stream,
                       W_access, W_read, 512, 512, 512, WpT);
    hipLaunchKernelGGL(tW_kern, dim3(16, 16), dim3(256), 0, stream,
                       W_merge, W_merge, 1024, 1024, 1024, WmT);
    hipLaunchKernelGGL((gemm_bf16<true>), dim3(16, 8), dim3(256), 0, stream,
                       qb, WpT, b_access, b_read, 512, aqrq, 1024, 1024);
    hipLaunchKernelGGL(k3_scale, dim3(128), dim3(256), 0, stream,
                       aqrq, kern_n, norm_k, scale);
    hipLaunchKernelGGL(k4_mfma, dim3(512), dim3(256), 0, stream,
                       aqrq, kern2, scale, resp);
    hipLaunchKernelGGL((gemm_bf16<false>), dim3(16, 8), dim3(256), 0, stream,
                       resp, WmT, b_merge, b_merge, 2048, out, 1024, 1024);
}

// Round 6
// 128.778 us; speedup vs baseline: 5.6354x; 1.2257x over previous
//
#include <hip/hip_runtime.h>
#include <hip/hip_bf16.h>
#include <math.h>

#define EPSF 1e-5f

typedef __attribute__((ext_vector_type(8))) short short8;
typedef __attribute__((ext_vector_type(4))) float f32x4;
typedef _Float16 half8 __attribute__((ext_vector_type(8)));

constexpr int Bc = 4, Tc = 512, Dc = 1024, Mc = 128, Hc = 8, DAc = 64, DMc = 128;
constexpr int BT = Bc * Tc;      // 2048
constexpr int Xc = DAc * DMc;    // 8192
constexpr int Rb = Tc * Hc;      // 4096 rows per batch (t*8+h)

__device__ __forceinline__ float softplus_f(float x) {
    return fmaxf(x, 0.f) + log1pf(expf(-fabsf(x)));
}
__device__ __forceinline__ short f2bf(float f) {
    __hip_bfloat16 h = __float2bfloat16(f);
    return *reinterpret_cast<short*>(&h);
}
__device__ __forceinline__ unsigned pk2(float a, float b) {
    return (unsigned)(unsigned short)f2bf(a) | ((unsigned)(unsigned short)f2bf(b) << 16);
}
// async global->LDS, 16B per lane; lds base must be wave-uniform
__device__ __forceinline__ void lds_load16(void* lds, const void* g) {
    __builtin_amdgcn_global_load_lds((const __attribute__((address_space(1))) int*)g,
                                     (__attribute__((address_space(3))) int*)lds, 16, 0, 0);
}

// ---------------- K0: ak = softplus(addresses), norm_k, akT (f16 [a2][mm]) ----------------
__global__ __launch_bounds__(256) void k0_ak(const float* __restrict__ addresses,
                                             float* __restrict__ ak_g,
                                             float* __restrict__ norm_k,
                                             _Float16* __restrict__ akT) {
    __shared__ float akl[Mc * DAc];
    int tid = threadIdx.x;
    for (int i = tid; i < Mc * DAc; i += 256) {
        float v = softplus_f(addresses[i]);
        ak_g[i] = v;
        akl[i] = v;
    }
    __syncthreads();
    if (tid < DAc) {
        float s = 0.f;
        for (int mm = 0; mm < Mc; mm++) s += akl[mm * DAc + tid];
        norm_k[tid] = s;
    }
    {   // akT[a2][mm] f16
        int a2 = tid >> 2, q = tid & 3;
#pragma unroll
        for (int j = 0; j < 32; j++)
            akT[a2 * Mc + q * 32 + j] = (_Float16)akl[(q * 32 + j) * DAc + a2];
    }
}

// ---------------- k1t: kern2[b][a][m][a2] (f16) = sum_mm matrix[b][mm][a][m]*ak[mm][a2] ----
__global__ __launch_bounds__(256) void k1t_mfma(const float* __restrict__ matrix,
                                                const _Float16* __restrict__ akT,
                                                _Float16* __restrict__ kern2) {
    __shared__ float T[32][132];
    __shared__ _Float16 At[128][40];
    int tid = threadIdx.x, lane = tid & 63, wid = tid >> 6;
    int l15 = lane & 15, lg = lane >> 4;
    int b = blockIdx.x >> 6, a = blockIdx.x & 63;
    int wr = wid & 1, wc = wid >> 1;

    half8 bfrag[2][4];
#pragma unroll
    for (int cf = 0; cf < 2; cf++)
#pragma unroll
        for (int ks = 0; ks < 4; ks++)
            bfrag[cf][ks] = *(const half8*)(akT + (wc * 32 + cf * 16 + l15) * Mc
                                            + ks * 32 + lg * 8);

    const float* msrc = matrix + (size_t)b * Mc * Xc + a * DMc;
    int r = tid >> 3, ms = (tid & 7) * 16;
    int tm = tid >> 1, tk0 = (tid & 1) * 16;

    f32x4 acc[4][2];
#pragma unroll
    for (int i = 0; i < 4; i++)
#pragma unroll
        for (int j = 0; j < 2; j++) acc[i][j] = (f32x4){0.f, 0.f, 0.f, 0.f};

    float4 ld[4];
#pragma unroll
    for (int j = 0; j < 4; j++)
        ld[j] = *(const float4*)(msrc + (size_t)r * Xc + ms + j * 4);

    for (int s = 0; s < 4; s++) {
#pragma unroll
        for (int j = 0; j < 4; j++) *(float4*)&T[r][ms + j * 4] = ld[j];
        __syncthreads();
        if (s < 3) {
#pragma unroll
            for (int j = 0; j < 4; j++)
                ld[j] = *(const float4*)(msrc + (size_t)((s + 1) * 32 + r) * Xc + ms + j * 4);
        }
        {
            half8 lo, hi;
#pragma unroll
            for (int j = 0; j < 8; j++) lo[j] = (_Float16)T[tk0 + j][tm];
#pragma unroll
            for (int j = 0; j < 8; j++) hi[j] = (_Float16)T[tk0 + 8 + j][tm];
            *(half8*)&At[tm][tk0] = lo;
            *(half8*)&At[tm][tk0 + 8] = hi;
        }
        __syncthreads();
#pragma unroll
        for (int rf = 0; rf < 4; rf++) {
            int row = wr * 64 + rf * 16 + l15;
            half8 af = *(const half8*)&At[row][lg * 8];
#pragma unroll
            for (int cf = 0; cf < 2; cf++)
                acc[rf][cf] = __builtin_amdgcn_mfma_f32_16x16x32_f16(
                    af, bfrag[cf][s], acc[rf][cf], 0, 0, 0);
        }
        __syncthreads();
    }
    _Float16* dst = kern2 + ((size_t)(b * 64 + a)) * Mc * DAc;
#pragma unroll
    for (int rf = 0; rf < 4; rf++)
#pragma unroll
        for (int cf = 0; cf < 2; cf++) {
            int a2 = wc * 32 + cf * 16 + l15;
#pragma unroll
            for (int i = 0; i < 4; i++) {
                int mrow = wr * 64 + rf * 16 + lg * 4 + i;
                dst[mrow * DAc + a2] = (_Float16)acc[rf][cf][i];
            }
        }
}

// ---------------- K2: kern_n[b,a2,d] = sum_m ak[m,a2] * normalizer[b,m,d] ----------------
// Grid 32: b = bid>>3, a2-chunk = bid&7 (8 a2 per block; thread-group g owns 2).
__global__ __launch_bounds__(256) void k2_kernn(const float* __restrict__ normalizer,
                                                const float* __restrict__ ak_g,
                                                float* __restrict__ kern_n) {
    __shared__ float akl[Mc * DAc];
    int tid = threadIdx.x;
    int b = blockIdx.x >> 3, ch = blockIdx.x & 7;
    for (int i = tid; i < Mc * DAc; i += 256) akl[i] = ak_g[i];
    __syncthreads();
    int d = tid & 63;
    int g = tid >> 6;  // 0..3
    int a2b = ch * 8 + g * 2;
    float acc0 = 0.f, acc1 = 0.f;
    const float* np = normalizer + (size_t)b * Mc * DAc + d;
    for (int mm = 0; mm < Mc; mm++) {
        float v = np[(size_t)mm * DAc];
        acc0 = fmaf(akl[mm * DAc + a2b + 0], v, acc0);
        acc1 = fmaf(akl[mm * DAc + a2b + 1], v, acc1);
    }
    kern_n[((size_t)b * DAc + a2b + 0) * DAc + d] = acc0;
    kern_n[((size_t)b * DAc + a2b + 1) * DAc + d] = acc1;
}

// ---------------- transpose+cvt: dst[n][1024] bf16 = W[k][n] ----------------
__global__ __launch_bounds__(256) void tW_kern(const float* __restrict__ S0,
                                               const float* __restrict__ S1,
                                               int N0, int st0, int st1,
                                               __hip_bfloat16* __restrict__ dst) {
    __shared__ float tile[64][65];
    int kt = blockIdx.x, nt = blockIdx.y;
    int n0 = nt * 64;
    const float* S; int stride, nb;
    if (n0 < N0) { S = S0; stride = st0; nb = n0; }
    else         { S = S1; stride = st1; nb = n0 - N0; }
    int t = threadIdx.x;
    {
        int kl = t >> 2, q = t & 3;
        const float* src = S + (size_t)(kt * 64 + kl) * stride + nb + q * 16;
#pragma unroll
        for (int j = 0; j < 4; j++) {
            float4 v = *(const float4*)(src + j * 4);
            tile[kl][q * 16 + j * 4 + 0] = v.x;
            tile[kl][q * 16 + j * 4 + 1] = v.y;
            tile[kl][q * 16 + j * 4 + 2] = v.z;
            tile[kl][q * 16 + j * 4 + 3] = v.w;
        }
    }
    __syncthreads();
    {
        int nl = t >> 2, q = t & 3;
        unsigned* d = (unsigned*)(dst + (size_t)(n0 + nl) * 1024 + kt * 64 + q * 16);
#pragma unroll
        for (int j = 0; j < 8; j++)
            d[j] = pk2(tile[q * 16 + j * 2][nl], tile[q * 16 + j * 2 + 1][nl]);
    }
}

// ---------------- convert query to bf16 ----------------
__global__ __launch_bounds__(256) void convq(const float* __restrict__ q,
                                             __hip_bfloat16* __restrict__ qb) {
    int i = (blockIdx.x * 256 + threadIdx.x) * 4;
    float4 v = *(const float4*)(q + i);
    unsigned* d = (unsigned*)(qb + i);
    d[0] = pk2(v.x, v.y);
    d[1] = pk2(v.z, v.w);
}

// ---------------- k3: scale[b][row] = 1/(den1*(sn/den1+EPS)) ----------------
__global__ __launch_bounds__(256) void k3_scale(const float* __restrict__ aqrq,
                                                const float* __restrict__ kern_n,
                                                const float* __restrict__ norm_k,
                                                float* __restrict__ scale) {
    __shared__ float knl[4096];
    __shared__ float nkl[64];
    int b = blockIdx.x >> 5, ch = blockIdx.x & 31;
    int t = threadIdx.x;
    {
        const float* src = kern_n + (size_t)b * 4096;
#pragma unroll
        for (int j = 0; j < 4; j++)
            *(float4*)&knl[t * 4 + j * 1024] = *(const float4*)(src + t * 4 + j * 1024);
    }
    if (t < 64) nkl[t] = norm_k[t];
    __syncthreads();
    int row = t >> 1, g = t & 1;
    int rg = ch * 128 + row;
    int t_ = rg >> 3, h = rg & 7;
    const float* aqp = aqrq + ((size_t)(b * Tc + t_)) * 1024 + h * 64;
    float rq[64];
#pragma unroll
    for (int j = 0; j < 16; j++) {
        float4 v = *(const float4*)(aqp + 512 + j * 4);
        rq[j * 4 + 0] = v.x; rq[j * 4 + 1] = v.y; rq[j * 4 + 2] = v.z; rq[j * 4 + 3] = v.w;
    }
    float aqh[32];
#pragma unroll
    for (int j = 0; j < 8; j++) {
        float4 v = *(const float4*)(aqp + g * 32 + j * 4);
        aqh[j * 4 + 0] = v.x; aqh[j * 4 + 1] = v.y; aqh[j * 4 + 2] = v.z; aqh[j * 4 + 3] = v.w;
    }
    float sn = 0.f, d1h = 0.f;
    for (int a2l = 0; a2l < 32; a2l++) {
        int a2 = g * 32 + a2l;
        const float4* kr = (const float4*)&knl[a2 * 64];
        float dot = 0.f;
#pragma unroll
        for (int d4 = 0; d4 < 16; d4++) {
            float4 kv = kr[d4];
            dot = fmaf(kv.x, rq[d4 * 4 + 0], dot);
            dot = fmaf(kv.y, rq[d4 * 4 + 1], dot);
            dot = fmaf(kv.z, rq[d4 * 4 + 2], dot);
            dot = fmaf(kv.w, rq[d4 * 4 + 3], dot);
        }
        sn = fmaf(aqh[a2l], dot, sn);
        d1h = fmaf(aqh[a2l], nkl[a2], d1h);
    }
    sn += __shfl_xor(sn, 1);
    d1h += __shfl_xor(d1h, 1);
    if (g == 0) {
        float den1 = d1h + EPSF;
        float den = sn / den1 + EPSF;
        scale[(size_t)b * Rb + rg] = 1.f / (den1 * den);
    }
}

// ---------------- bf16 MFMA GEMM: C[M][N] = A[M][K] @ BT[N][K]^T + bias ----------------
// BM=128, BN=64, BK=64 -> grid (M/128, N/64) = 16x16 = 256 blocks.
template <bool SOFTPLUS>
__global__ __launch_bounds__(256) void gemm_bf16(const __hip_bfloat16* __restrict__ A,
                                                 const __hip_bfloat16* __restrict__ BT_,
                                                 const float* __restrict__ bias0,
                                                 const float* __restrict__ bias1, int N0,
                                                 float* __restrict__ C, int N, int K) {
    __shared__ short Ab[2][128 * 64];
    __shared__ short Bb[2][64 * 64];
    int tid = threadIdx.x, lane = tid & 63, wid = tid >> 6;
    int l15 = lane & 15, lg = lane >> 4;
    int rowblk = blockIdx.x * 128, colblk = blockIdx.y * 64;
    int wr = wid & 1, wc = wid >> 1;
    int srow = lane >> 3;
    int sk = ((lane & 7) ^ srow) * 8;

    f32x4 acc[4][2];
#pragma unroll
    for (int i = 0; i < 4; i++)
#pragma unroll
        for (int j = 0; j < 2; j++) acc[i][j] = (f32x4){0.f, 0.f, 0.f, 0.f};

    auto stage = [&](int kbase, int buf) {
#pragma unroll
        for (int j = 0; j < 4; j++) {
            int c = wid * 4 + j;
            int row = c * 8 + srow;
            lds_load16(&Ab[buf][c * 512], A + (size_t)(rowblk + row) * K + kbase + sk);
        }
#pragma unroll
        for (int j = 0; j < 2; j++) {
            int c = wid * 2 + j;
            int row = c * 8 + srow;
            lds_load16(&Bb[buf][c * 512], BT_ + (size_t)(colblk + row) * K + kbase + sk);
        }
    };
    stage(0, 0);
    __syncthreads();
    int cur = 0;
    int nks = K >> 6;
    for (int ks = 0; ks < nks; ks++) {
        if (ks + 1 < nks) stage((ks + 1) << 6, cur ^ 1);
#pragma unroll
        for (int kh = 0; kh < 2; kh++) {
            short8 af[4], bfr[2];
#pragma unroll
            for (int rf = 0; rf < 4; rf++) {
                int row = wr * 64 + rf * 16 + l15;
                int ksw = (kh * 32 + lg * 8) ^ ((row & 7) << 3);
                af[rf] = *(const short8*)&Ab[cur][row * 64 + ksw];
            }
#pragma unroll
            for (int cf = 0; cf < 2; cf++) {
                int col = wc * 32 + cf * 16 + l15;
                int ksw = (kh * 32 + lg * 8) ^ ((col & 7) << 3);
                bfr[cf] = *(const short8*)&Bb[cur][col * 64 + ksw];
            }
#pragma unroll
            for (int rf = 0; rf < 4; rf++)
#pragma unroll
                for (int cf = 0; cf < 2; cf++)
                    acc[rf][cf] = __builtin_amdgcn_mfma_f32_16x16x32_bf16(
                        af[rf], bfr[cf], acc[rf][cf], 0, 0, 0);
        }
        __syncthreads();
        cur ^= 1;
    }
#pragma unroll
    for (int cf = 0; cf < 2; cf++) {
        int col = colblk + wc * 32 + cf * 16 + l15;
        float bv = (col < N0) ? bias0[col] : bias1[col - N0];
#pragma unroll
        for (int rf = 0; rf < 4; rf++) {
            int rbase = rowblk + wr * 64 + rf * 16 + lg * 4;
#pragma unroll
            for (int i = 0; i < 4; i++) {
                float v = acc[rf][cf][i] + bv;
                if (SOFTPLUS) v = softplus_f(v);
                C[(size_t)(rbase + i) * N + col] = v;
            }
        }
    }
}

// ---------------- k4: main contraction over a-slices, f16 MFMA, a-step=2 ----------------
// num[row,m] = sum_a rq[row,a] * sum_a2 aq[row,a2] * kern2[b][a][m][a2]
__global__ __launch_bounds__(256) void k4_mfma(const float* __restrict__ aqrq,
                                               const _Float16* __restrict__ kern2,
                                               const float* __restrict__ scale,
                                               __hip_bfloat16* __restrict__ resp) {
    __shared__ _Float16 Bb[2][2][64 * 64];  // [buf][slice][m][a2 swizzled]
    __shared__ float rql[64][68];
    __shared__ float scl[64];
    int tid = threadIdx.x, lane = tid & 63, wid = tid >> 6;
    int l15 = lane & 15, lg = lane >> 4;
    int b = blockIdx.x >> 7;
    int rc = (blockIdx.x >> 1) & 63;
    int mh = blockIdx.x & 1;
    int rowbase = rc * 64;
    int wr = wid & 1, wc = wid >> 1;

    auto stageB = [&](int a_, int buf, int sl) {
#pragma unroll
        for (int j = 0; j < 2; j++) {
            int c = wid * 2 + j;
            int m = c * 8 + (lane >> 3);
            int sa = ((lane & 7) ^ (lane >> 3)) * 8;
            lds_load16(&Bb[buf][sl][c * 512],
                       kern2 + (((size_t)(b * 64 + a_)) * Mc + mh * 64 + m) * DAc + sa);
        }
    };
    stageB(0, 0, 0);
    stageB(1, 0, 1);

    // aq fragments straight from global (once)
    half8 aqp[2][2];
#pragma unroll
    for (int rf = 0; rf < 2; rf++)
#pragma unroll
        for (int kh = 0; kh < 2; kh++) {
            int rg = rowbase + wr * 32 + rf * 16 + l15;
            int t_ = rg >> 3, h = rg & 7;
            const float* s = aqrq + ((size_t)(b * Tc + t_)) * 1024 + h * 64 + kh * 32 + lg * 8;
            float4 v0 = *(const float4*)(s);
            float4 v1 = *(const float4*)(s + 4);
            half8 r;
            r[0] = (_Float16)v0.x; r[1] = (_Float16)v0.y;
            r[2] = (_Float16)v0.z; r[3] = (_Float16)v0.w;
            r[4] = (_Float16)v1.x; r[5] = (_Float16)v1.y;
            r[6] = (_Float16)v1.z; r[7] = (_Float16)v1.w;
            aqp[rf][kh] = r;
        }
    {   // rq rows -> LDS (16 floats per thread)
        int row = tid >> 2, q = tid & 3;
        int rg = rowbase + row;
        int t_ = rg >> 3, h = rg & 7;
        const float* src = aqrq + ((size_t)(b * Tc + t_)) * 1024 + 512 + h * 64 + q * 16;
#pragma unroll
        for (int j = 0; j < 4; j++) {
            float4 w = *(const float4*)(src + j * 4);
            rql[row][q * 16 + j * 4 + 0] = w.x;
            rql[row][q * 16 + j * 4 + 1] = w.y;
            rql[row][q * 16 + j * 4 + 2] = w.z;
            rql[row][q * 16 + j * 4 + 3] = w.w;
        }
    }
    if (tid < 64) scl[tid] = scale[(size_t)b * Rb + rowbase + tid];
    __syncthreads();

    f32x4 acc[2][2];
#pragma unroll
    for (int i = 0; i < 2; i++)
#pragma unroll
        for (int j = 0; j < 2; j++) acc[i][j] = (f32x4){0.f, 0.f, 0.f, 0.f};

    int cur = 0;
    for (int it = 0; it < 32; it++) {
        if (it < 31) {
            stageB(it * 2 + 2, cur ^ 1, 0);
            stageB(it * 2 + 3, cur ^ 1, 1);
        }
#pragma unroll
        for (int as = 0; as < 2; as++) {
            int a = it * 2 + as;
            _Float16 h0 = (_Float16)rql[wr * 32 + l15][a];
            _Float16 h1 = (_Float16)rql[wr * 32 + 16 + l15][a];
            half8 rb0 = {h0, h0, h0, h0, h0, h0, h0, h0};
            half8 rb1 = {h1, h1, h1, h1, h1, h1, h1, h1};
#pragma unroll
            for (int kh = 0; kh < 2; kh++) {
#pragma unroll
                for (int cf = 0; cf < 2; cf++) {
                    int mloc = wc * 32 + cf * 16 + l15;
                    int ch = (kh * 4 + lg) ^ (mloc & 7);
                    half8 bf = *(const half8*)&Bb[cur][as][mloc * 64 + ch * 8];
                    acc[0][cf] = __builtin_amdgcn_mfma_f32_16x16x32_f16(
                        aqp[0][kh] * rb0, bf, acc[0][cf], 0, 0, 0);
                    acc[1][cf] = __builtin_amdgcn_mfma_f32_16x16x32_f16(
                        aqp[1][kh] * rb1, bf, acc[1][cf], 0, 0, 0);
                }
            }
        }
        __syncthreads();
        cur ^= 1;
    }
#pragma unroll
    for (int rf = 0; rf < 2; rf++) {
#pragma unroll
        for (int i = 0; i < 4; i++) {
            int rl = wr * 32 + rf * 16 + lg * 4 + i;
            int rg = rowbase + rl;
            float s = scl[rl];
            int t_ = rg >> 3, h = rg & 7;
            __hip_bfloat16* dst = resp + ((size_t)(b * Tc + t_)) * 1024 + h * DMc + mh * 64;
#pragma unroll
            for (int cf = 0; cf < 2; cf++) {
                int m = wc * 32 + cf * 16 + l15;
                dst[m] = __float2bfloat16(acc[rf][cf][i] * s);
            }
        }
    }
}

extern "C" void kernel_launch(void* const* d_in, const int* in_sizes, int n_in,
                              void* d_out, int out_size, void* d_ws, size_t ws_size,
                              hipStream_t stream) {
    const float* query      = (const float*)d_in[0];
    const float* matrix     = (const float*)d_in[1];
    const float* normalizer = (const float*)d_in[2];
    const float* addresses  = (const float*)d_in[3];
    const float* W_access   = (const float*)d_in[4];
    const float* b_access   = (const float*)d_in[5];
    const float* W_read     = (const float*)d_in[6];
    const float* b_read     = (const float*)d_in[7];
    const float* W_merge    = (const float*)d_in[8];
    const float* b_merge    = (const float*)d_in[9];
    float* out = (float*)d_out;
    (void)in_sizes; (void)n_in; (void)out_size; (void)ws_size;

    float* ws     = (float*)d_ws;
    float* ak     = ws;                        // 8192
    float* norm_k = ws + 8192;                 // 64 (+pad)
    float* kern_n = ws + 8320;                 // 16384
    float* scale  = ws + 24704;                // 16384
    _Float16* akT = (_Float16*)(ws + 41088);   // 8192 f16 = 4096 f
    float* aqrq   = ws + 65536;                // 2,097,152 f32
    _Float16* kern2 = (_Float16*)(ws + 2162688);              // 2,097,152 f16 = 1,048,576 f
    __hip_bfloat16* qb   = (__hip_bfloat16*)(ws + 3211264);   // 1,048,576 f
    __hip_bfloat16* resp = (__hip_bfloat16*)(ws + 4259840);   // 1,048,576 f
    __hip_bfloat16* WpT  = (__hip_bfloat16*)(ws + 5308416);   // 524,288 f
    __hip_bfloat16* WmT  = (__hip_bfloat16*)(ws + 5832704);   // 524,288 f
    // total 6,356,992 floats = 25.4 MB

    hipLaunchKernelGGL(k0_ak, dim3(1), dim3(256), 0, stream, addresses, ak, norm_k, akT);
    hipLaunchKernelGGL(k1t_mfma, dim3(256), dim3(256), 0, stream, matrix, akT, kern2);
    hipLaunchKernelGGL(k2_kernn, dim3(32), dim3(256), 0, stream, normalizer, ak, kern_n);
    hipLaunchKernelGGL(convq, dim3(2048), dim3(256), 0, stream, query, qb);
    hipLaunchKernelGGL(tW_kern, dim3(16, 16), dim3(256), 0, stream,
                       W_access, W_read, 512, 512, 512, WpT);
    hipLaunchKernelGGL(tW_kern, dim3(16, 16), dim3(256), 0, stream,
                       W_merge, W_merge, 1024, 1024, 1024, WmT);
    hipLaunchKernelGGL((gemm_bf16<true>), dim3(16, 16), dim3(256), 0, stream,
                       qb, WpT, b_access, b_read, 512, aqrq, 1024, 1024);
    hipLaunchKernelGGL(k3_scale, dim3(128), dim3(256), 0, stream,
                       aqrq, kern_n, norm_k, scale);
    hipLaunchKernelGGL(k4_mfma, dim3(512), dim3(256), 0, stream,
                       aqrq, kern2, scale, resp);
    hipLaunchKernelGGL((gemm_bf16<false>), dim3(16, 16), dim3(256), 0, stream,
                       resp, WmT, b_merge, b_merge, 2048, out, 1024, 1024);
}

// Round 7
// 105.709 us; speedup vs baseline: 6.8653x; 1.2182x over previous
//
#include <hip/hip_runtime.h>
#include <hip/hip_bf16.h>
#include <math.h>

#define EPSF 1e-5f

typedef __attribute__((ext_vector_type(8))) short short8;
typedef __attribute__((ext_vector_type(4))) float f32x4;
typedef _Float16 half8 __attribute__((ext_vector_type(8)));

constexpr int Bc = 4, Tc = 512, Dc = 1024, Mc = 128, Hc = 8, DAc = 64, DMc = 128;
constexpr int BT = Bc * Tc;      // 2048
constexpr int Xc = DAc * DMc;    // 8192
constexpr int Rb = Tc * Hc;      // 4096 rows per batch (t*8+h)

__device__ __forceinline__ float softplus_f(float x) {
    return fmaxf(x, 0.f) + log1pf(expf(-fabsf(x)));
}
__device__ __forceinline__ short f2bf(float f) {
    __hip_bfloat16 h = __float2bfloat16(f);
    return *reinterpret_cast<short*>(&h);
}
__device__ __forceinline__ unsigned pk2(float a, float b) {
    return (unsigned)(unsigned short)f2bf(a) | ((unsigned)(unsigned short)f2bf(b) << 16);
}
// async global->LDS, 16B per lane; lds base must be wave-uniform
__device__ __forceinline__ void lds_load16(void* lds, const void* g) {
    __builtin_amdgcn_global_load_lds((const __attribute__((address_space(1))) int*)g,
                                     (__attribute__((address_space(3))) int*)lds, 16, 0, 0);
}

// ---------------- prep: block 0 = k0 (ak/norm_k/akT); 1..2048 = convq; then 2x tW ------
__global__ __launch_bounds__(256) void prep_kern(const float* __restrict__ addresses,
                                                 float* __restrict__ ak_g,
                                                 float* __restrict__ norm_k,
                                                 _Float16* __restrict__ akT,
                                                 const float* __restrict__ query,
                                                 __hip_bfloat16* __restrict__ qb,
                                                 const float* __restrict__ W_access,
                                                 const float* __restrict__ W_read,
                                                 __hip_bfloat16* __restrict__ WpT,
                                                 const float* __restrict__ W_merge,
                                                 __hip_bfloat16* __restrict__ WmT) {
    __shared__ float smem[Mc * DAc];   // 32KB; reused as 64x65 tile by tW branches
    int bid = blockIdx.x;
    int t = threadIdx.x;
    if (bid == 0) {
        for (int i = t; i < Mc * DAc; i += 256) {
            float v = softplus_f(addresses[i]);
            ak_g[i] = v;
            smem[i] = v;
        }
        __syncthreads();
        if (t < DAc) {
            float s = 0.f;
            for (int mm = 0; mm < Mc; mm++) s += smem[mm * DAc + t];
            norm_k[t] = s;
        }
        {
            int a2 = t >> 2, q = t & 3;
#pragma unroll
            for (int j = 0; j < 32; j++)
                akT[a2 * Mc + q * 32 + j] = (_Float16)smem[(q * 32 + j) * DAc + a2];
        }
        return;
    }
    if (bid <= 2048) {
        int i = ((bid - 1) * 256 + t) * 4;
        float4 v = *(const float4*)(query + i);
        unsigned* d = (unsigned*)(qb + i);
        d[0] = pk2(v.x, v.y);
        d[1] = pk2(v.z, v.w);
        return;
    }
    // tW branches: 64x64 transpose+cvt tiles
    float (*tile)[65] = (float(*)[65])smem;
    const float* S; int stride, nb, n0, kt;
    __hip_bfloat16* dst;
    if (bid < 2305) {
        int idx = bid - 2049;           // 256 tiles for [W_access | W_read]
        kt = idx & 15;
        n0 = (idx >> 4) * 64;
        if (n0 < 512) { S = W_access; nb = n0; }
        else          { S = W_read;   nb = n0 - 512; }
        stride = 512;
        dst = WpT;
    } else {
        int idx = bid - 2305;
        kt = idx & 15;
        n0 = (idx >> 4) * 64;
        S = W_merge; nb = n0; stride = 1024;
        dst = WmT;
    }
    {
        int kl = t >> 2, q = t & 3;
        const float* src = S + (size_t)(kt * 64 + kl) * stride + nb + q * 16;
#pragma unroll
        for (int j = 0; j < 4; j++) {
            float4 v = *(const float4*)(src + j * 4);
            tile[kl][q * 16 + j * 4 + 0] = v.x;
            tile[kl][q * 16 + j * 4 + 1] = v.y;
            tile[kl][q * 16 + j * 4 + 2] = v.z;
            tile[kl][q * 16 + j * 4 + 3] = v.w;
        }
    }
    __syncthreads();
    {
        int nl = t >> 2, q = t & 3;
        unsigned* d = (unsigned*)(dst + (size_t)(n0 + nl) * 1024 + kt * 64 + q * 16);
#pragma unroll
        for (int j = 0; j < 8; j++)
            d[j] = pk2(tile[q * 16 + j * 2][nl], tile[q * 16 + j * 2 + 1][nl]);
    }
}

// ---------------- k1t: kern2[b][a][m][a2] (f16) = sum_mm matrix[b][mm][a][m]*ak[mm][a2] ----
__global__ __launch_bounds__(256) void k1t_mfma(const float* __restrict__ matrix,
                                                const _Float16* __restrict__ akT,
                                                _Float16* __restrict__ kern2) {
    __shared__ float T[32][132];
    __shared__ _Float16 At[128][40];
    int tid = threadIdx.x, lane = tid & 63, wid = tid >> 6;
    int l15 = lane & 15, lg = lane >> 4;
    int b = blockIdx.x >> 6, a = blockIdx.x & 63;
    int wr = wid & 1, wc = wid >> 1;

    half8 bfrag[2][4];
#pragma unroll
    for (int cf = 0; cf < 2; cf++)
#pragma unroll
        for (int ks = 0; ks < 4; ks++)
            bfrag[cf][ks] = *(const half8*)(akT + (wc * 32 + cf * 16 + l15) * Mc
                                            + ks * 32 + lg * 8);

    const float* msrc = matrix + (size_t)b * Mc * Xc + a * DMc;
    int r = tid >> 3, ms = (tid & 7) * 16;
    int tm = tid >> 1, tk0 = (tid & 1) * 16;

    f32x4 acc[4][2];
#pragma unroll
    for (int i = 0; i < 4; i++)
#pragma unroll
        for (int j = 0; j < 2; j++) acc[i][j] = (f32x4){0.f, 0.f, 0.f, 0.f};

    float4 ld[4];
#pragma unroll
    for (int j = 0; j < 4; j++)
        ld[j] = *(const float4*)(msrc + (size_t)r * Xc + ms + j * 4);

    for (int s = 0; s < 4; s++) {
#pragma unroll
        for (int j = 0; j < 4; j++) *(float4*)&T[r][ms + j * 4] = ld[j];
        __syncthreads();
        if (s < 3) {
#pragma unroll
            for (int j = 0; j < 4; j++)
                ld[j] = *(const float4*)(msrc + (size_t)((s + 1) * 32 + r) * Xc + ms + j * 4);
        }
        {
            half8 lo, hi;
#pragma unroll
            for (int j = 0; j < 8; j++) lo[j] = (_Float16)T[tk0 + j][tm];
#pragma unroll
            for (int j = 0; j < 8; j++) hi[j] = (_Float16)T[tk0 + 8 + j][tm];
            *(half8*)&At[tm][tk0] = lo;
            *(half8*)&At[tm][tk0 + 8] = hi;
        }
        __syncthreads();
#pragma unroll
        for (int rf = 0; rf < 4; rf++) {
            int row = wr * 64 + rf * 16 + l15;
            half8 af = *(const half8*)&At[row][lg * 8];
#pragma unroll
            for (int cf = 0; cf < 2; cf++)
                acc[rf][cf] = __builtin_amdgcn_mfma_f32_16x16x32_f16(
                    af, bfrag[cf][s], acc[rf][cf], 0, 0, 0);
        }
        __syncthreads();
    }
    _Float16* dst = kern2 + ((size_t)(b * 64 + a)) * Mc * DAc;
#pragma unroll
    for (int rf = 0; rf < 4; rf++)
#pragma unroll
        for (int cf = 0; cf < 2; cf++) {
            int a2 = wc * 32 + cf * 16 + l15;
#pragma unroll
            for (int i = 0; i < 4; i++) {
                int mrow = wr * 64 + rf * 16 + lg * 4 + i;
                dst[mrow * DAc + a2] = (_Float16)acc[rf][cf][i];
            }
        }
}

// ---------------- K2: kern_n[b,a2,d] = sum_m ak[m,a2] * normalizer[b,m,d] ----------------
__global__ __launch_bounds__(256) void k2_kernn(const float* __restrict__ normalizer,
                                                const float* __restrict__ ak_g,
                                                float* __restrict__ kern_n) {
    __shared__ float akl[Mc * DAc];
    int tid = threadIdx.x;
    int b = blockIdx.x >> 3, ch = blockIdx.x & 7;
    for (int i = tid; i < Mc * DAc; i += 256) akl[i] = ak_g[i];
    __syncthreads();
    int d = tid & 63;
    int g = tid >> 6;
    int a2b = ch * 8 + g * 2;
    float acc0 = 0.f, acc1 = 0.f;
    const float* np = normalizer + (size_t)b * Mc * DAc + d;
    for (int mm = 0; mm < Mc; mm++) {
        float v = np[(size_t)mm * DAc];
        acc0 = fmaf(akl[mm * DAc + a2b + 0], v, acc0);
        acc1 = fmaf(akl[mm * DAc + a2b + 1], v, acc1);
    }
    kern_n[((size_t)b * DAc + a2b + 0) * DAc + d] = acc0;
    kern_n[((size_t)b * DAc + a2b + 1) * DAc + d] = acc1;
}

// ---------------- k3: scale[b][row] = 1/(den1*(sn/den1+EPS)) (f16 aqrq) ----------------
__global__ __launch_bounds__(256) void k3_scale(const _Float16* __restrict__ aqrq16,
                                                const float* __restrict__ kern_n,
                                                const float* __restrict__ norm_k,
                                                float* __restrict__ scale) {
    __shared__ float knl[4096];
    __shared__ float nkl[64];
    int b = blockIdx.x >> 5, ch = blockIdx.x & 31;
    int t = threadIdx.x;
    {
        const float* src = kern_n + (size_t)b * 4096;
#pragma unroll
        for (int j = 0; j < 4; j++)
            *(float4*)&knl[t * 4 + j * 1024] = *(const float4*)(src + t * 4 + j * 1024);
    }
    if (t < 64) nkl[t] = norm_k[t];
    __syncthreads();
    int row = t >> 1, g = t & 1;
    int rg = ch * 128 + row;
    int t_ = rg >> 3, h = rg & 7;
    const _Float16* aqp = aqrq16 + ((size_t)(b * Tc + t_)) * 1024 + h * 64;
    float rq[64];
#pragma unroll
    for (int j = 0; j < 8; j++) {
        half8 v = *(const half8*)(aqp + 512 + j * 8);
#pragma unroll
        for (int k = 0; k < 8; k++) rq[j * 8 + k] = (float)v[k];
    }
    float aqh[32];
#pragma unroll
    for (int j = 0; j < 4; j++) {
        half8 v = *(const half8*)(aqp + g * 32 + j * 8);
#pragma unroll
        for (int k = 0; k < 8; k++) aqh[j * 8 + k] = (float)v[k];
    }
    float sn = 0.f, d1h = 0.f;
    for (int a2l = 0; a2l < 32; a2l++) {
        int a2 = g * 32 + a2l;
        const float4* kr = (const float4*)&knl[a2 * 64];
        float dot = 0.f;
#pragma unroll
        for (int d4 = 0; d4 < 16; d4++) {
            float4 kv = kr[d4];
            dot = fmaf(kv.x, rq[d4 * 4 + 0], dot);
            dot = fmaf(kv.y, rq[d4 * 4 + 1], dot);
            dot = fmaf(kv.z, rq[d4 * 4 + 2], dot);
            dot = fmaf(kv.w, rq[d4 * 4 + 3], dot);
        }
        sn = fmaf(aqh[a2l], dot, sn);
        d1h = fmaf(aqh[a2l], nkl[a2], d1h);
    }
    sn += __shfl_xor(sn, 1);
    d1h += __shfl_xor(d1h, 1);
    if (g == 0) {
        float den1 = d1h + EPSF;
        float den = sn / den1 + EPSF;
        scale[(size_t)b * Rb + rg] = 1.f / (den1 * den);
    }
}

// ---------------- bf16 MFMA GEMM: C[M][N] = A[M][K] @ BT[N][K]^T + bias ----------------
// BM=64, BN=64, BK=64 -> gemm1 grid (32,16), gemm2 grid (32,16); 2 blocks/CU.
template <bool SOFTPLUS, typename OutT>
__global__ __launch_bounds__(256) void gemm_bf16(const __hip_bfloat16* __restrict__ A,
                                                 const __hip_bfloat16* __restrict__ BT_,
                                                 const float* __restrict__ bias0,
                                                 const float* __restrict__ bias1, int N0,
                                                 OutT* __restrict__ C, int N, int K) {
    __shared__ short Ab[2][64 * 64];
    __shared__ short Bb[2][64 * 64];
    int tid = threadIdx.x, lane = tid & 63, wid = tid >> 6;
    int l15 = lane & 15, lg = lane >> 4;
    int rowblk = blockIdx.x * 64, colblk = blockIdx.y * 64;
    int wr = wid & 1, wc = wid >> 1;
    int srow = lane >> 3;
    int sk = ((lane & 7) ^ srow) * 8;

    f32x4 acc[2][2];
#pragma unroll
    for (int i = 0; i < 2; i++)
#pragma unroll
        for (int j = 0; j < 2; j++) acc[i][j] = (f32x4){0.f, 0.f, 0.f, 0.f};

    auto stage = [&](int kbase, int buf) {
#pragma unroll
        for (int j = 0; j < 2; j++) {
            int c = wid * 2 + j;
            int row = c * 8 + srow;
            lds_load16(&Ab[buf][c * 512], A + (size_t)(rowblk + row) * K + kbase + sk);
            lds_load16(&Bb[buf][c * 512], BT_ + (size_t)(colblk + row) * K + kbase + sk);
        }
    };
    stage(0, 0);
    __syncthreads();
    int cur = 0;
    int nks = K >> 6;
    for (int ks = 0; ks < nks; ks++) {
        if (ks + 1 < nks) stage((ks + 1) << 6, cur ^ 1);
#pragma unroll
        for (int kh = 0; kh < 2; kh++) {
            short8 af[2], bfr[2];
#pragma unroll
            for (int rf = 0; rf < 2; rf++) {
                int row = wr * 32 + rf * 16 + l15;
                int ksw = (kh * 32 + lg * 8) ^ ((row & 7) << 3);
                af[rf] = *(const short8*)&Ab[cur][row * 64 + ksw];
            }
#pragma unroll
            for (int cf = 0; cf < 2; cf++) {
                int col = wc * 32 + cf * 16 + l15;
                int ksw = (kh * 32 + lg * 8) ^ ((col & 7) << 3);
                bfr[cf] = *(const short8*)&Bb[cur][col * 64 + ksw];
            }
#pragma unroll
            for (int rf = 0; rf < 2; rf++)
#pragma unroll
                for (int cf = 0; cf < 2; cf++)
                    acc[rf][cf] = __builtin_amdgcn_mfma_f32_16x16x32_bf16(
                        af[rf], bfr[cf], acc[rf][cf], 0, 0, 0);
        }
        __syncthreads();
        cur ^= 1;
    }
#pragma unroll
    for (int cf = 0; cf < 2; cf++) {
        int col = colblk + wc * 32 + cf * 16 + l15;
        float bv = (col < N0) ? bias0[col] : bias1[col - N0];
#pragma unroll
        for (int rf = 0; rf < 2; rf++) {
            int rbase = rowblk + wr * 32 + rf * 16 + lg * 4;
#pragma unroll
            for (int i = 0; i < 4; i++) {
                float v = acc[rf][cf][i] + bv;
                if (SOFTPLUS) v = softplus_f(v);
                C[(size_t)(rbase + i) * N + col] = (OutT)v;
            }
        }
    }
}

// ---------------- k4: main contraction over a-slices, f16 MFMA, a-step=4 ----------------
// num[row,m] = sum_a rq[row,a] * sum_a2 aq[row,a2] * kern2[b][a][m][a2]
__global__ __launch_bounds__(256) void k4_mfma(const _Float16* __restrict__ aqrq16,
                                               const _Float16* __restrict__ kern2,
                                               const float* __restrict__ scale,
                                               __hip_bfloat16* __restrict__ resp) {
    __shared__ _Float16 Bb[2][4][64 * 64];  // 64KB: [buf][slice][m][a2 swizzled]
    __shared__ _Float16 rql[64][72];        // 9.2KB
    __shared__ float scl[64];
    int tid = threadIdx.x, lane = tid & 63, wid = tid >> 6;
    int l15 = lane & 15, lg = lane >> 4;
    int b = blockIdx.x >> 7;
    int rc = (blockIdx.x >> 1) & 63;
    int mh = blockIdx.x & 1;
    int rowbase = rc * 64;
    int wr = wid & 1, wc = wid >> 1;

    auto stageB = [&](int a_, int buf, int sl) {
#pragma unroll
        for (int j = 0; j < 2; j++) {
            int c = wid * 2 + j;
            int m = c * 8 + (lane >> 3);
            int sa = ((lane & 7) ^ (lane >> 3)) * 8;
            lds_load16(&Bb[buf][sl][c * 512],
                       kern2 + (((size_t)(b * 64 + a_)) * Mc + mh * 64 + m) * DAc + sa);
        }
    };
#pragma unroll
    for (int sl = 0; sl < 4; sl++) stageB(sl, 0, sl);

    // aq fragments straight from global f16 (loop-invariant)
    half8 aqp[2][2];
#pragma unroll
    for (int rf = 0; rf < 2; rf++)
#pragma unroll
        for (int kh = 0; kh < 2; kh++) {
            int rg = rowbase + wr * 32 + rf * 16 + l15;
            int t_ = rg >> 3, h = rg & 7;
            aqp[rf][kh] = *(const half8*)(aqrq16 + ((size_t)(b * Tc + t_)) * 1024
                                          + h * 64 + kh * 32 + lg * 8);
        }
    {   // rq rows -> LDS f16 (16 halves per thread)
        int row = tid >> 2, q = tid & 3;
        int rg = rowbase + row;
        int t_ = rg >> 3, h = rg & 7;
        const _Float16* src = aqrq16 + ((size_t)(b * Tc + t_)) * 1024 + 512 + h * 64 + q * 16;
        *(half8*)&rql[row][q * 16] = *(const half8*)(src);
        *(half8*)&rql[row][q * 16 + 8] = *(const half8*)(src + 8);
    }
    if (tid < 64) scl[tid] = scale[(size_t)b * Rb + rowbase + tid];
    __syncthreads();

    f32x4 acc[2][2];
#pragma unroll
    for (int i = 0; i < 2; i++)
#pragma unroll
        for (int j = 0; j < 2; j++) acc[i][j] = (f32x4){0.f, 0.f, 0.f, 0.f};

    int cur = 0;
    for (int it = 0; it < 16; it++) {
        if (it < 15) {
#pragma unroll
            for (int sl = 0; sl < 4; sl++) stageB(it * 4 + 4 + sl, cur ^ 1, sl);
        }
#pragma unroll
        for (int as = 0; as < 4; as++) {
            int a = it * 4 + as;
            _Float16 h0 = rql[wr * 32 + l15][a];
            _Float16 h1 = rql[wr * 32 + 16 + l15][a];
            half8 rb0 = {h0, h0, h0, h0, h0, h0, h0, h0};
            half8 rb1 = {h1, h1, h1, h1, h1, h1, h1, h1};
#pragma unroll
            for (int kh = 0; kh < 2; kh++) {
#pragma unroll
                for (int cf = 0; cf < 2; cf++) {
                    int mloc = wc * 32 + cf * 16 + l15;
                    int ch = (kh * 4 + lg) ^ (mloc & 7);
                    half8 bf = *(const half8*)&Bb[cur][as][mloc * 64 + ch * 8];
                    acc[0][cf] = __builtin_amdgcn_mfma_f32_16x16x32_f16(
                        aqp[0][kh] * rb0, bf, acc[0][cf], 0, 0, 0);
                    acc[1][cf] = __builtin_amdgcn_mfma_f32_16x16x32_f16(
                        aqp[1][kh] * rb1, bf, acc[1][cf], 0, 0, 0);
                }
            }
        }
        __syncthreads();
        cur ^= 1;
    }
#pragma unroll
    for (int rf = 0; rf < 2; rf++) {
#pragma unroll
        for (int i = 0; i < 4; i++) {
            int rl = wr * 32 + rf * 16 + lg * 4 + i;
            int rg = rowbase + rl;
            float s = scl[rl];
            int t_ = rg >> 3, h = rg & 7;
            __hip_bfloat16* dst = resp + ((size_t)(b * Tc + t_)) * 1024 + h * DMc + mh * 64;
#pragma unroll
            for (int cf = 0; cf < 2; cf++) {
                int m = wc * 32 + cf * 16 + l15;
                dst[m] = __float2bfloat16(acc[rf][cf][i] * s);
            }
        }
    }
}

extern "C" void kernel_launch(void* const* d_in, const int* in_sizes, int n_in,
                              void* d_out, int out_size, void* d_ws, size_t ws_size,
                              hipStream_t stream) {
    const float* query      = (const float*)d_in[0];
    const float* matrix     = (const float*)d_in[1];
    const float* normalizer = (const float*)d_in[2];
    const float* addresses  = (const float*)d_in[3];
    const float* W_access   = (const float*)d_in[4];
    const float* b_access   = (const float*)d_in[5];
    const float* W_read     = (const float*)d_in[6];
    const float* b_read     = (const float*)d_in[7];
    const float* W_merge    = (const float*)d_in[8];
    const float* b_merge    = (const float*)d_in[9];
    float* out = (float*)d_out;
    (void)in_sizes; (void)n_in; (void)out_size; (void)ws_size;

    float* ws     = (float*)d_ws;
    float* ak     = ws;                        // 8192
    float* norm_k = ws + 8192;                 // 64 (+pad)
    float* kern_n = ws + 8320;                 // 16384
    float* scale  = ws + 24704;                // 16384
    _Float16* akT = (_Float16*)(ws + 41088);   // 8192 f16
    _Float16* aqrq16 = (_Float16*)(ws + 65536);               // 2,097,152 f16 = 1,048,576 f
    _Float16* kern2  = (_Float16*)(ws + 1114112);             // 2,097,152 f16 = 1,048,576 f
    __hip_bfloat16* qb   = (__hip_bfloat16*)(ws + 2162688);   // 1,048,576 f
    __hip_bfloat16* resp = (__hip_bfloat16*)(ws + 3211264);   // 1,048,576 f
    __hip_bfloat16* WpT  = (__hip_bfloat16*)(ws + 4259840);   // 524,288 f
    __hip_bfloat16* WmT  = (__hip_bfloat16*)(ws + 4784128);   // 524,288 f
    // total 5,308,416 floats = 21.2 MB

    hipLaunchKernelGGL(prep_kern, dim3(2561), dim3(256), 0, stream,
                       addresses, ak, norm_k, akT, query, qb,
                       W_access, W_read, WpT, W_merge, WmT);
    hipLaunchKernelGGL(k1t_mfma, dim3(256), dim3(256), 0, stream, matrix, akT, kern2);
    hipLaunchKernelGGL(k2_kernn, dim3(32), dim3(256), 0, stream, normalizer, ak, kern_n);
    hipLaunchKernelGGL((gemm_bf16<true, _Float16>), dim3(32, 16), dim3(256), 0, stream,
                       qb, WpT, b_access, b_read, 512, aqrq16, 1024, 1024);
    hipLaunchKernelGGL(k3_scale, dim3(128), dim3(256), 0, stream,
                       aqrq16, kern_n, norm_k, scale);
    hipLaunchKernelGGL(k4_mfma, dim3(512), dim3(256), 0, stream,
                       aqrq16, kern2, scale, resp);
    hipLaunchKernelGGL((gemm_bf16<false, float>), dim3(32, 16), dim3(256), 0, stream,
                       resp, WmT, b_merge, b_merge, 2048, out, 1024, 1024);
}

// Round 8
// 96.506 us; speedup vs baseline: 7.5199x; 1.0954x over previous
//
#include <hip/hip_runtime.h>
#include <hip/hip_bf16.h>
#include <math.h>

#define EPSF 1e-5f

typedef __attribute__((ext_vector_type(8))) short short8;
typedef __attribute__((ext_vector_type(4))) float f32x4;
typedef _Float16 half8 __attribute__((ext_vector_type(8)));

constexpr int Bc = 4, Tc = 512, Dc = 1024, Mc = 128, Hc = 8, DAc = 64, DMc = 128;
constexpr int BT = Bc * Tc;      // 2048
constexpr int Xc = DAc * DMc;    // 8192
constexpr int Rb = Tc * Hc;      // 4096 rows per batch (t*8+h)

__device__ __forceinline__ float softplus_f(float x) {
    return fmaxf(x, 0.f) + log1pf(expf(-fabsf(x)));
}
__device__ __forceinline__ short f2bf(float f) {
    __hip_bfloat16 h = __float2bfloat16(f);
    return *reinterpret_cast<short*>(&h);
}
__device__ __forceinline__ unsigned pk2(float a, float b) {
    return (unsigned)(unsigned short)f2bf(a) | ((unsigned)(unsigned short)f2bf(b) << 16);
}
// async global->LDS, 16B per lane; lds base must be wave-uniform
__device__ __forceinline__ void lds_load16(void* lds, const void* g) {
    __builtin_amdgcn_global_load_lds((const __attribute__((address_space(1))) int*)g,
                                     (__attribute__((address_space(3))) int*)lds, 16, 0, 0);
}

// ---------------- front: k1t | k2 | norm_k | convq | tW --------------------------------
// blocks [0,256): k1t  (b=bid>>6, a=bid&63)
// blocks [256,288): k2 (idx=bid-256: b=idx>>3, ch=idx&7)
// block 288: norm_k
// blocks [289,2337): convq
// blocks [2337,2593): tW -> WpT ; [2593,2849): tW -> WmT
__global__ __launch_bounds__(256) void front_kern(
        const float* __restrict__ addresses,
        const float* __restrict__ matrix,
        const float* __restrict__ normalizer,
        const float* __restrict__ query,
        const float* __restrict__ W_access,
        const float* __restrict__ W_read,
        const float* __restrict__ W_merge,
        _Float16* __restrict__ kern2,
        float* __restrict__ kern_n,
        float* __restrict__ norm_k,
        __hip_bfloat16* __restrict__ qb,
        __hip_bfloat16* __restrict__ WpT,
        __hip_bfloat16* __restrict__ WmT) {
    __shared__ float smem[8192];   // 32KB, carved per branch
    int bid = blockIdx.x;
    int tid = threadIdx.x;

    if (bid < 256) {
        // ---- k1t: kern2[b][a][m][a2] = sum_mm matrix[b][mm][a][m]*softplus(addr[mm][a2])
        float (*T)[132] = (float(*)[132])smem;                    // 4224 f
        _Float16 (*At)[40] = (_Float16(*)[40])(smem + 4224);      // 2560 f
        int lane = tid & 63, wid = tid >> 6;
        int l15 = lane & 15, lg = lane >> 4;
        int b = bid >> 6, a = bid & 63;
        int wr = wid & 1, wc = wid >> 1;

        half8 bfrag[2][4];
#pragma unroll
        for (int cf = 0; cf < 2; cf++) {
            int a2 = wc * 32 + cf * 16 + l15;
#pragma unroll
            for (int ks = 0; ks < 4; ks++)
#pragma unroll
                for (int j = 0; j < 8; j++) {
                    int mm = ks * 32 + lg * 8 + j;
                    bfrag[cf][ks][j] = (_Float16)softplus_f(addresses[mm * 64 + a2]);
                }
        }

        const float* msrc = matrix + (size_t)b * Mc * Xc + a * DMc;
        int r = tid >> 3, ms = (tid & 7) * 16;
        int tm = tid >> 1, tk0 = (tid & 1) * 16;

        f32x4 acc[4][2];
#pragma unroll
        for (int i = 0; i < 4; i++)
#pragma unroll
            for (int j = 0; j < 2; j++) acc[i][j] = (f32x4){0.f, 0.f, 0.f, 0.f};

        float4 ld[4];
#pragma unroll
        for (int j = 0; j < 4; j++)
            ld[j] = *(const float4*)(msrc + (size_t)r * Xc + ms + j * 4);

        for (int s = 0; s < 4; s++) {
#pragma unroll
            for (int j = 0; j < 4; j++) *(float4*)&T[r][ms + j * 4] = ld[j];
            __syncthreads();
            if (s < 3) {
#pragma unroll
                for (int j = 0; j < 4; j++)
                    ld[j] = *(const float4*)(msrc + (size_t)((s + 1) * 32 + r) * Xc + ms + j * 4);
            }
            {
                half8 lo, hi;
#pragma unroll
                for (int j = 0; j < 8; j++) lo[j] = (_Float16)T[tk0 + j][tm];
#pragma unroll
                for (int j = 0; j < 8; j++) hi[j] = (_Float16)T[tk0 + 8 + j][tm];
                *(half8*)&At[tm][tk0] = lo;
                *(half8*)&At[tm][tk0 + 8] = hi;
            }
            __syncthreads();
#pragma unroll
            for (int rf = 0; rf < 4; rf++) {
                int row = wr * 64 + rf * 16 + l15;
                half8 af = *(const half8*)&At[row][lg * 8];
#pragma unroll
                for (int cf = 0; cf < 2; cf++)
                    acc[rf][cf] = __builtin_amdgcn_mfma_f32_16x16x32_f16(
                        af, bfrag[cf][s], acc[rf][cf], 0, 0, 0);
            }
            __syncthreads();
        }
        _Float16* dst = kern2 + ((size_t)(b * 64 + a)) * Mc * DAc;
#pragma unroll
        for (int rf = 0; rf < 4; rf++)
#pragma unroll
            for (int cf = 0; cf < 2; cf++) {
                int a2 = wc * 32 + cf * 16 + l15;
#pragma unroll
                for (int i = 0; i < 4; i++) {
                    int mrow = wr * 64 + rf * 16 + lg * 4 + i;
                    dst[mrow * DAc + a2] = (_Float16)acc[rf][cf][i];
                }
            }
        return;
    }
    if (bid < 288) {
        // ---- k2: kern_n[b,a2,d] = sum_m softplus(addr[m,a2]) * normalizer[b,m,d]
        int idx = bid - 256;
        int b = idx >> 3, ch = idx & 7;
        for (int i = tid; i < Mc * DAc; i += 256) smem[i] = softplus_f(addresses[i]);
        __syncthreads();
        int d = tid & 63;
        int g = tid >> 6;
        int a2b = ch * 8 + g * 2;
        float acc0 = 0.f, acc1 = 0.f;
        const float* np = normalizer + (size_t)b * Mc * DAc + d;
        for (int mm = 0; mm < Mc; mm++) {
            float v = np[(size_t)mm * DAc];
            acc0 = fmaf(smem[mm * DAc + a2b + 0], v, acc0);
            acc1 = fmaf(smem[mm * DAc + a2b + 1], v, acc1);
        }
        kern_n[((size_t)b * DAc + a2b + 0) * DAc + d] = acc0;
        kern_n[((size_t)b * DAc + a2b + 1) * DAc + d] = acc1;
        return;
    }
    if (bid == 288) {
        // ---- norm_k[a2] = sum_mm softplus(addr[mm,a2])
        for (int i = tid; i < Mc * DAc; i += 256) smem[i] = softplus_f(addresses[i]);
        __syncthreads();
        if (tid < DAc) {
            float s = 0.f;
            for (int mm = 0; mm < Mc; mm++) s += smem[mm * DAc + tid];
            norm_k[tid] = s;
        }
        return;
    }
    if (bid < 2337) {
        // ---- convq
        int i = ((bid - 289) * 256 + tid) * 4;
        float4 v = *(const float4*)(query + i);
        unsigned* d = (unsigned*)(qb + i);
        d[0] = pk2(v.x, v.y);
        d[1] = pk2(v.z, v.w);
        return;
    }
    // ---- tW: 64x64 transpose+cvt
    float (*tile)[65] = (float(*)[65])smem;
    const float* S; int stride, nb, n0, kt;
    __hip_bfloat16* dst;
    if (bid < 2593) {
        int idx = bid - 2337;
        kt = idx & 15;
        n0 = (idx >> 4) * 64;
        if (n0 < 512) { S = W_access; nb = n0; }
        else          { S = W_read;   nb = n0 - 512; }
        stride = 512;
        dst = WpT;
    } else {
        int idx = bid - 2593;
        kt = idx & 15;
        n0 = (idx >> 4) * 64;
        S = W_merge; nb = n0; stride = 1024;
        dst = WmT;
    }
    {
        int kl = tid >> 2, q = tid & 3;
        const float* src = S + (size_t)(kt * 64 + kl) * stride + nb + q * 16;
#pragma unroll
        for (int j = 0; j < 4; j++) {
            float4 v = *(const float4*)(src + j * 4);
            tile[kl][q * 16 + j * 4 + 0] = v.x;
            tile[kl][q * 16 + j * 4 + 1] = v.y;
            tile[kl][q * 16 + j * 4 + 2] = v.z;
            tile[kl][q * 16 + j * 4 + 3] = v.w;
        }
    }
    __syncthreads();
    {
        int nl = tid >> 2, q = tid & 3;
        unsigned* d = (unsigned*)(dst + (size_t)(n0 + nl) * 1024 + kt * 64 + q * 16);
#pragma unroll
        for (int j = 0; j < 8; j++)
            d[j] = pk2(tile[q * 16 + j * 2][nl], tile[q * 16 + j * 2 + 1][nl]);
    }
}

// ---------------- bf16 MFMA GEMM: C[M][N] = A[M][K] @ BT[N][K]^T + bias ----------------
// BM=64, BN=64, BK=128 (2 sub-tiles per drain) -> grid (32,16); LDS 64KB, 2 blocks/CU.
template <bool SOFTPLUS, typename OutT>
__global__ __launch_bounds__(256) void gemm_bf16(const __hip_bfloat16* __restrict__ A,
                                                 const __hip_bfloat16* __restrict__ BT_,
                                                 const float* __restrict__ bias0,
                                                 const float* __restrict__ bias1, int N0,
                                                 OutT* __restrict__ C, int N, int K) {
    __shared__ short Ab[2][2][64 * 64];
    __shared__ short Bb[2][2][64 * 64];
    int tid = threadIdx.x, lane = tid & 63, wid = tid >> 6;
    int l15 = lane & 15, lg = lane >> 4;
    int rowblk = blockIdx.x * 64, colblk = blockIdx.y * 64;
    int wr = wid & 1, wc = wid >> 1;
    int srow = lane >> 3;
    int sk = ((lane & 7) ^ srow) * 8;

    f32x4 acc[2][2];
#pragma unroll
    for (int i = 0; i < 2; i++)
#pragma unroll
        for (int j = 0; j < 2; j++) acc[i][j] = (f32x4){0.f, 0.f, 0.f, 0.f};

    auto stage = [&](int kbase, int buf, int sub) {
#pragma unroll
        for (int j = 0; j < 2; j++) {
            int c = wid * 2 + j;
            int row = c * 8 + srow;
            lds_load16(&Ab[buf][sub][c * 512], A + (size_t)(rowblk + row) * K + kbase + sk);
            lds_load16(&Bb[buf][sub][c * 512], BT_ + (size_t)(colblk + row) * K + kbase + sk);
        }
    };
    stage(0, 0, 0);
    stage(64, 0, 1);
    __syncthreads();
    int cur = 0;
    int nks = K >> 7;   // 8
    for (int ks = 0; ks < nks; ks++) {
        if (ks + 1 < nks) {
            stage((ks + 1) << 7, cur ^ 1, 0);
            stage(((ks + 1) << 7) + 64, cur ^ 1, 1);
        }
#pragma unroll
        for (int sub = 0; sub < 2; sub++) {
#pragma unroll
            for (int kh = 0; kh < 2; kh++) {
                short8 af[2], bfr[2];
#pragma unroll
                for (int rf = 0; rf < 2; rf++) {
                    int row = wr * 32 + rf * 16 + l15;
                    int ksw = (kh * 32 + lg * 8) ^ ((row & 7) << 3);
                    af[rf] = *(const short8*)&Ab[cur][sub][row * 64 + ksw];
                }
#pragma unroll
                for (int cf = 0; cf < 2; cf++) {
                    int col = wc * 32 + cf * 16 + l15;
                    int ksw = (kh * 32 + lg * 8) ^ ((col & 7) << 3);
                    bfr[cf] = *(const short8*)&Bb[cur][sub][col * 64 + ksw];
                }
#pragma unroll
                for (int rf = 0; rf < 2; rf++)
#pragma unroll
                    for (int cf = 0; cf < 2; cf++)
                        acc[rf][cf] = __builtin_amdgcn_mfma_f32_16x16x32_bf16(
                            af[rf], bfr[cf], acc[rf][cf], 0, 0, 0);
            }
        }
        __syncthreads();
        cur ^= 1;
    }
#pragma unroll
    for (int cf = 0; cf < 2; cf++) {
        int col = colblk + wc * 32 + cf * 16 + l15;
        float bv = (col < N0) ? bias0[col] : bias1[col - N0];
#pragma unroll
        for (int rf = 0; rf < 2; rf++) {
            int rbase = rowblk + wr * 32 + rf * 16 + lg * 4;
#pragma unroll
            for (int i = 0; i < 4; i++) {
                float v = acc[rf][cf][i] + bv;
                if (SOFTPLUS) v = softplus_f(v);
                C[(size_t)(rbase + i) * N + col] = (OutT)v;
            }
        }
    }
}

// ---------------- k4: scale pre-phase + main contraction (f16 MFMA, a-step=4) ----------
// scale[row] = 1/(den1*(sn/den1+EPS)); num[row,m] = sum_a rq[a] sum_a2 aq[a2] kern2[b][a][m][a2]
__global__ __launch_bounds__(256) void k4_mfma(const _Float16* __restrict__ aqrq16,
                                               const _Float16* __restrict__ kern2,
                                               const float* __restrict__ kern_n,
                                               const float* __restrict__ norm_k,
                                               __hip_bfloat16* __restrict__ resp) {
    __shared__ _Float16 Bb[2][4][64 * 64];  // 64KB
    __shared__ _Float16 rql[64][72];        // 9.2KB
    __shared__ float scl[64];
    __shared__ float nkl[64];
    int tid = threadIdx.x, lane = tid & 63, wid = tid >> 6;
    int l15 = lane & 15, lg = lane >> 4;
    int b = blockIdx.x >> 7;
    int rc = (blockIdx.x >> 1) & 63;
    int mh = blockIdx.x & 1;
    int rowbase = rc * 64;
    int wr = wid & 1, wc = wid >> 1;
    float* knl = (float*)&Bb[1][0][0];      // 16KB alias, dead until first prefetch

    auto stageB = [&](int a_, int buf, int sl) {
#pragma unroll
        for (int j = 0; j < 2; j++) {
            int c = wid * 2 + j;
            int m = c * 8 + (lane >> 3);
            int sa = ((lane & 7) ^ (lane >> 3)) * 8;
            lds_load16(&Bb[buf][sl][c * 512],
                       kern2 + (((size_t)(b * 64 + a_)) * Mc + mh * 64 + m) * DAc + sa);
        }
    };
#pragma unroll
    for (int sl = 0; sl < 4; sl++) stageB(sl, 0, sl);
    {   // kern_n[b] -> knl (16KB, async)
#pragma unroll
        for (int j = 0; j < 4; j++) {
            int c = wid * 4 + j;
            lds_load16(knl + c * 256, kern_n + (size_t)b * 4096 + c * 256 + lane * 4);
        }
    }

    // aq fragments (loop-invariant)
    half8 aqp[2][2];
#pragma unroll
    for (int rf = 0; rf < 2; rf++)
#pragma unroll
        for (int kh = 0; kh < 2; kh++) {
            int rg = rowbase + wr * 32 + rf * 16 + l15;
            int t_ = rg >> 3, h = rg & 7;
            aqp[rf][kh] = *(const half8*)(aqrq16 + ((size_t)(b * Tc + t_)) * 1024
                                          + h * 64 + kh * 32 + lg * 8);
        }
    {   // rq rows -> LDS f16
        int row = tid >> 2, q = tid & 3;
        int rg = rowbase + row;
        int t_ = rg >> 3, h = rg & 7;
        const _Float16* src = aqrq16 + ((size_t)(b * Tc + t_)) * 1024 + 512 + h * 64 + q * 16;
        *(half8*)&rql[row][q * 16] = *(const half8*)(src);
        *(half8*)&rql[row][q * 16 + 8] = *(const half8*)(src + 8);
    }
    if (tid < 64) nkl[tid] = norm_k[tid];
    __syncthreads();

    {   // scale phase: 4 threads per row, 16 a2 each
        int row = tid >> 2, c = tid & 3;
        int rg = rowbase + row;
        int t_ = rg >> 3, h = rg & 7;
        const _Float16* aqg = aqrq16 + ((size_t)(b * Tc + t_)) * 1024 + h * 64 + c * 16;
        half8 a0 = *(const half8*)(aqg);
        half8 a1 = *(const half8*)(aqg + 8);
        float aqv[16];
#pragma unroll
        for (int j = 0; j < 8; j++) { aqv[j] = (float)a0[j]; aqv[8 + j] = (float)a1[j]; }
        float rqv[64];
#pragma unroll
        for (int j8 = 0; j8 < 8; j8++) {
            half8 v = *(const half8*)&rql[row][j8 * 8];
#pragma unroll
            for (int k = 0; k < 8; k++) rqv[j8 * 8 + k] = (float)v[k];
        }
        float sn = 0.f, d1 = 0.f;
        for (int a2l = 0; a2l < 16; a2l++) {
            int a2 = c * 16 + a2l;
            const float4* kr = (const float4*)(knl + a2 * 64);
            float dot = 0.f;
#pragma unroll
            for (int d4 = 0; d4 < 16; d4++) {
                float4 kv = kr[d4];
                dot = fmaf(kv.x, rqv[d4 * 4 + 0], dot);
                dot = fmaf(kv.y, rqv[d4 * 4 + 1], dot);
                dot = fmaf(kv.z, rqv[d4 * 4 + 2], dot);
                dot = fmaf(kv.w, rqv[d4 * 4 + 3], dot);
            }
            sn = fmaf(aqv[a2l], dot, sn);
            d1 = fmaf(aqv[a2l], nkl[a2], d1);
        }
        sn += __shfl_xor(sn, 1); sn += __shfl_xor(sn, 2);
        d1 += __shfl_xor(d1, 1); d1 += __shfl_xor(d1, 2);
        if (c == 0) {
            float den1 = d1 + EPSF;
            float den = sn / den1 + EPSF;
            scl[row] = 1.f / (den1 * den);
        }
    }
    __syncthreads();   // scl ready; knl reads done -> Bb[1] reusable

    f32x4 acc[2][2];
#pragma unroll
    for (int i = 0; i < 2; i++)
#pragma unroll
        for (int j = 0; j < 2; j++) acc[i][j] = (f32x4){0.f, 0.f, 0.f, 0.f};

    int cur = 0;
    for (int it = 0; it < 16; it++) {
        if (it < 15) {
#pragma unroll
            for (int sl = 0; sl < 4; sl++) stageB(it * 4 + 4 + sl, cur ^ 1, sl);
        }
#pragma unroll
        for (int as = 0; as < 4; as++) {
            int a = it * 4 + as;
            _Float16 h0 = rql[wr * 32 + l15][a];
            _Float16 h1 = rql[wr * 32 + 16 + l15][a];
            half8 rb0 = {h0, h0, h0, h0, h0, h0, h0, h0};
            half8 rb1 = {h1, h1, h1, h1, h1, h1, h1, h1};
#pragma unroll
            for (int kh = 0; kh < 2; kh++) {
#pragma unroll
                for (int cf = 0; cf < 2; cf++) {
                    int mloc = wc * 32 + cf * 16 + l15;
                    int ch = (kh * 4 + lg) ^ (mloc & 7);
                    half8 bf = *(const half8*)&Bb[cur][as][mloc * 64 + ch * 8];
                    acc[0][cf] = __builtin_amdgcn_mfma_f32_16x16x32_f16(
                        aqp[0][kh] * rb0, bf, acc[0][cf], 0, 0, 0);
                    acc[1][cf] = __builtin_amdgcn_mfma_f32_16x16x32_f16(
                        aqp[1][kh] * rb1, bf, acc[1][cf], 0, 0, 0);
                }
            }
        }
        __syncthreads();
        cur ^= 1;
    }
#pragma unroll
    for (int rf = 0; rf < 2; rf++) {
#pragma unroll
        for (int i = 0; i < 4; i++) {
            int rl = wr * 32 + rf * 16 + lg * 4 + i;
            int rg = rowbase + rl;
            float s = scl[rl];
            int t_ = rg >> 3, h = rg & 7;
            __hip_bfloat16* dst = resp + ((size_t)(b * Tc + t_)) * 1024 + h * DMc + mh * 64;
#pragma unroll
            for (int cf = 0; cf < 2; cf++) {
                int m = wc * 32 + cf * 16 + l15;
                dst[m] = __float2bfloat16(acc[rf][cf][i] * s);
            }
        }
    }
}

extern "C" void kernel_launch(void* const* d_in, const int* in_sizes, int n_in,
                              void* d_out, int out_size, void* d_ws, size_t ws_size,
                              hipStream_t stream) {
    const float* query      = (const float*)d_in[0];
    const float* matrix     = (const float*)d_in[1];
    const float* normalizer = (const float*)d_in[2];
    const float* addresses  = (const float*)d_in[3];
    const float* W_access   = (const float*)d_in[4];
    const float* b_access   = (const float*)d_in[5];
    const float* W_read     = (const float*)d_in[6];
    const float* b_read     = (const float*)d_in[7];
    const float* W_merge    = (const float*)d_in[8];
    const float* b_merge    = (const float*)d_in[9];
    float* out = (float*)d_out;
    (void)in_sizes; (void)n_in; (void)out_size; (void)ws_size;

    float* ws     = (float*)d_ws;
    float* norm_k = ws;                        // 64 (+pad to 128)
    float* kern_n = ws + 128;                  // 16384
    _Float16* aqrq16 = (_Float16*)(ws + 16512);               // 2,097,152 f16 = 1,048,576 f
    _Float16* kern2  = (_Float16*)(ws + 1065088);             // 2,097,152 f16 = 1,048,576 f
    __hip_bfloat16* qb   = (__hip_bfloat16*)(ws + 2113664);   // 1,048,576 f
    __hip_bfloat16* resp = (__hip_bfloat16*)(ws + 3162240);   // 1,048,576 f
    __hip_bfloat16* WpT  = (__hip_bfloat16*)(ws + 4210816);   // 524,288 f
    __hip_bfloat16* WmT  = (__hip_bfloat16*)(ws + 4735104);   // 524,288 f
    // total 5,259,392 floats = 21.0 MB

    hipLaunchKernelGGL(front_kern, dim3(2849), dim3(256), 0, stream,
                       addresses, matrix, normalizer, query,
                       W_access, W_read, W_merge,
                       kern2, kern_n, norm_k, qb, WpT, WmT);
    hipLaunchKernelGGL((gemm_bf16<true, _Float16>), dim3(32, 16), dim3(256), 0, stream,
                       qb, WpT, b_access, b_read, 512, aqrq16, 1024, 1024);
    hipLaunchKernelGGL(k4_mfma, dim3(512), dim3(256), 0, stream,
                       aqrq16, kern2, kern_n, norm_k, resp);
    hipLaunchKernelGGL((gemm_bf16<false, float>), dim3(32, 16), dim3(256), 0, stream,
                       resp, WmT, b_merge, b_merge, 2048, out, 1024, 1024);
}